// Round 11
// baseline (210.625 us; speedup 1.0000x reference)
//
#include <hip/hip_runtime.h>
#include <stdint.h>

// GeoAwarePooling B=4, N=40000, C=128, V=4.
// xyz is broadcast across views -> per-point MLP runs once over B*N points.
// v11: 5 launches (init folded into k_A blk0; k_global folded into k_B
// prologue; k_final decodes global_xyz itself). k_A back to 512-thr
// (16 waves/CU) + xyz prefetch. k_B keeps deep loop + z prefetch.

#define NPTS 40000
#define CD   128

typedef __attribute__((ext_vector_type(8))) short bf8_t;
typedef __attribute__((ext_vector_type(4))) float f4_t;

__device__ __forceinline__ unsigned short f2bfu(float f){
  unsigned u = __float_as_uint(f);
  u += 0x7FFFu + ((u>>16)&1u);               // RNE
  return (unsigned short)(u>>16);
}
__device__ __forceinline__ float bfhi_f(float f){   // f rounded to bf16, as f32
  return __uint_as_float(((unsigned)f2bfu(f))<<16);
}
__device__ __forceinline__ unsigned pk2(float a, float b){
  return (unsigned)f2bfu(a) | ((unsigned)f2bfu(b)<<16);
}
__device__ __forceinline__ float uplo(unsigned u){ return __uint_as_float(u<<16); }
__device__ __forceinline__ float uphi(unsigned u){ return __uint_as_float(u & 0xFFFF0000u); }
__device__ __forceinline__ unsigned fenc(float f){  // order-preserving key
  unsigned u = __float_as_uint(f);
  return (u & 0x80000000u) ? ~u : (u | 0x80000000u);
}
__device__ __forceinline__ float fdec(unsigned k){
  return (k & 0x80000000u) ? __uint_as_float(k & 0x7FFFFFFFu) : __uint_as_float(~k);
}
__device__ __forceinline__ bf8_t bc8(uint4 v){ return __builtin_bit_cast(bf8_t, v); }

// ---------------------------------------------------------------------------
// Phase A: y=xyz@W1+b1 (K=32 MFMA, hi/lo split, fp32-exact); h=relu(LN1(y));
// z=(h@W2+b2 normalized, pre-affine) -> global in B-FRAGMENT layout:
// z2g[(it*4+ks)*64+lane]. 512 thr (8 waves, 16 waves/CU), grid 512, 3 reps,
// next-rep xyz prefetch. Block 0 also initializes ws accumulators (their
// consumers are all in later kernels).
// ---------------------------------------------------------------------------
__global__ __launch_bounds__(512)
void k_A(const float* __restrict__ xyz,
         const float* __restrict__ W1, const float* __restrict__ b1,
         const float* __restrict__ g1, const float* __restrict__ be1,
         const float* __restrict__ W2, const float* __restrict__ b2,
         uint4* __restrict__ z2g,
         unsigned* __restrict__ kmax, unsigned* __restrict__ kmin,
         float* __restrict__ denom, float* __restrict__ pool_acc)
{
  __shared__ uint4 W2F[2048];        // 32 KiB  [frag=ks*8+mto][lane]
  __shared__ uint4 A1F[512];         // 8 KiB   [mto][lane]
  __shared__ uint4 Hb4[8][16][16];   // 32 KiB  per-wave transpose tile
  __shared__ uint2 P1u[32], P2u[32], P3u[32];

  const int tid = threadIdx.x;
  if (blockIdx.x == 0){
    if (tid < 512){ kmax[tid] = 0u; kmin[tid] = 0xFFFFFFFFu; }
    for (int i = tid; i < 2048; i += 512) pool_acc[i] = 0.f;
    if (tid < 16) denom[tid] = 0.f;
  }
  for (int e = tid; e < 2048; e += 512){
    int f = e >> 6, l = e & 63;
    int ks = f >> 3, mto = f & 7;
    int lm = l & 15, lg = l >> 4;
    int ci = 32*ks + 8*lg, co = 16*mto + lm;
    uint4 v;
    v.x = pk2(W2[(ci+0)*CD+co], W2[(ci+1)*CD+co]);
    v.y = pk2(W2[(ci+2)*CD+co], W2[(ci+3)*CD+co]);
    v.z = pk2(W2[(ci+4)*CD+co], W2[(ci+5)*CD+co]);
    v.w = pk2(W2[(ci+6)*CD+co], W2[(ci+7)*CD+co]);
    W2F[e] = v;
  }
  {
    int mto = tid >> 6, l = tid & 63;
    int lm = l & 15, lg = l >> 4;
    int c = 16*mto + lm;
    float w0=W1[c], w1=W1[CD+c], w2=W1[2*CD+c], bb=b1[c];
    uint4 v = {0u,0u,0u,0u};
    if (lg==0){ v.x=pk2(w0,w1); v.y=pk2(w2,w0); v.z=pk2(w1,w2);
                v.w=pk2(w0-bfhi_f(w0), w1-bfhi_f(w1)); }
    else if (lg==1){ v.x=pk2(w2-bfhi_f(w2), bb); v.y=pk2(bb-bfhi_f(bb),0.f); }
    A1F[tid] = v;
  }
  if (tid < 32){
    int t4 = tid*4;
    uint2 v;
    v.x = pk2(g1[t4], g1[t4+1]);  v.y = pk2(g1[t4+2], g1[t4+3]);  P1u[tid] = v;
    v.x = pk2(be1[t4],be1[t4+1]); v.y = pk2(be1[t4+2],be1[t4+3]); P2u[tid] = v;
    v.x = pk2(b2[t4], b2[t4+1]);  v.y = pk2(b2[t4+2], b2[t4+3]);  P3u[tid] = v;
  }
  __syncthreads();

  const int wave = tid>>6, lane = tid&63;
  const int m = lane&15, g = lane>>4;
  const int b  = blockIdx.x >> 7;              // 128 blocks per batch
  const int wb = (blockIdx.x & 127)*8 + wave;  // 0..1023 within batch
  const int swz = m & 7;
  const float* xyzb = xyz + (size_t)3*b*NPTS;
  uint2* Hb2 = (uint2*)&Hb4[wave][0][0];

  int tb = wb;                                 // always < 2500 at entry
  float px, py, pz;
  {
    int n0 = tb*16 + m;
    px = xyzb[n0]; py = xyzb[NPTS+n0]; pz = xyzb[2*NPTS+n0];
  }

#pragma unroll 1
  for (int rep = 0; rep < 3; ++rep){
    if (tb >= 2500) break;
    const int tbn = tb + 1024;
    const bool hasn = (rep < 2) && (tbn < 2500);
    float pxn, pyn, pzn;
    if (hasn){
      int nn = tbn*16 + m;
      pxn = xyzb[nn]; pyn = xyzb[NPTS+nn]; pzn = xyzb[2*NPTS+nn];
    }
    const int it = b*2500 + tb;

    uint4 B1u = {0u,0u,0u,0u};
    if (g==0){ B1u.x = pk2(px,py); B1u.y = pk2(pz, px-bfhi_f(px));
               B1u.z = pk2(py-bfhi_f(py), pz-bfhi_f(pz)); B1u.w = pk2(px,py); }
    else if (g==1){ B1u.x = pk2(pz, 1.0f); B1u.y = pk2(1.0f, 0.f); }
    bf8_t B1 = bc8(B1u);

    // GEMM1
    f4_t acc[8];
#pragma unroll
    for (int mt=0;mt<8;++mt)
      acc[mt] = __builtin_amdgcn_mfma_f32_16x16x32_bf16(
                    bc8(A1F[mt*64+lane]), B1, (f4_t){0.f,0.f,0.f,0.f}, 0,0,0);

    // LN1
    float s1=0.f, s2=0.f;
#pragma unroll
    for (int mt=0;mt<8;++mt)
#pragma unroll
      for (int r=0;r<4;++r){ float v=acc[mt][r]; s1+=v; s2=fmaf(v,v,s2); }
    s1 += __shfl_xor(s1,16); s1 += __shfl_xor(s1,32);
    s2 += __shfl_xor(s2,16); s2 += __shfl_xor(s2,32);
    float mu = s1*(1.f/128.f);
    float rs = rsqrtf(fmaxf(s2*(1.f/128.f)-mu*mu,0.f)+1e-5f);

    // affine+relu -> write h pairs into swizzled transpose tile
#pragma unroll
    for (int mt=0;mt<8;++mt){
      uint2 gv = P1u[4*mt+g], bv = P2u[4*mt+g];
      float h0 = fmaxf(0.f, fmaf((acc[mt][0]-mu)*rs, uplo(gv.x), uplo(bv.x)));
      float h1 = fmaxf(0.f, fmaf((acc[mt][1]-mu)*rs, uphi(gv.x), uphi(bv.x)));
      float h2 = fmaxf(0.f, fmaf((acc[mt][2]-mu)*rs, uplo(gv.y), uplo(bv.y)));
      float h3 = fmaxf(0.f, fmaf((acc[mt][3]-mu)*rs, uphi(gv.y), uphi(bv.y)));
      uint2 wv; wv.x = pk2(h0,h1); wv.y = pk2(h2,h3);
      int slot = ((mt>>1)*4 + 2*(mt&1) + (g>>1)) ^ swz;
      Hb2[(m*16 + slot)*2 + (g&1)] = wv;
    }

    // GEMM2: B-frags from transpose tile, A-frags from W2F
    f4_t a2[8];
#pragma unroll
    for (int mt=0;mt<8;++mt) a2[mt]=(f4_t){0.f,0.f,0.f,0.f};
#pragma unroll
    for (int ks=0;ks<4;++ks){
      bf8_t Bf = bc8(Hb4[wave][m][(ks*4+g)^swz]);
#pragma unroll
      for (int mto=0;mto<8;++mto)
        a2[mto] = __builtin_amdgcn_mfma_f32_16x16x32_bf16(
                      bc8(W2F[(ks*8+mto)*64+lane]), Bf, a2[mto], 0,0,0);
    }

    // +b2, LN2
    s1=0.f; s2=0.f;
#pragma unroll
    for (int mt=0;mt<8;++mt){
      uint2 bv = P3u[4*mt+g];
      a2[mt][0]+=uplo(bv.x); a2[mt][1]+=uphi(bv.x);
      a2[mt][2]+=uplo(bv.y); a2[mt][3]+=uphi(bv.y);
#pragma unroll
      for (int r=0;r<4;++r){ float v=a2[mt][r]; s1+=v; s2=fmaf(v,v,s2); }
    }
    s1 += __shfl_xor(s1,16); s1 += __shfl_xor(s1,32);
    s2 += __shfl_xor(s2,16); s2 += __shfl_xor(s2,32);
    mu = s1*(1.f/128.f);
    rs = rsqrtf(fmaxf(s2*(1.f/128.f)-mu*mu,0.f)+1e-5f);

    // z pairs -> transpose tile -> read frags -> coalesced global store
#pragma unroll
    for (int mt=0;mt<8;++mt){
      float z0=(a2[mt][0]-mu)*rs, z1=(a2[mt][1]-mu)*rs;
      float z2v=(a2[mt][2]-mu)*rs, z3=(a2[mt][3]-mu)*rs;
      uint2 wv; wv.x=pk2(z0,z1); wv.y=pk2(z2v,z3);
      int slot = ((mt>>1)*4 + 2*(mt&1) + (g>>1)) ^ swz;
      Hb2[(m*16 + slot)*2 + (g&1)] = wv;
    }
#pragma unroll
    for (int ks=0;ks<4;++ks){
      uint4 frag = Hb4[wave][m][(ks*4+g)^swz];
      z2g[(size_t)(it*4+ks)*64 + lane] = frag;
    }

    if (hasn){ px = pxn; py = pyn; pz = pzn; }
    tb = tbn;
  }
}

// per-channel max/min scan of z2 (frag layout). wave w handles k-slice w.
// 1000 blocks x 10 tiles.
__global__ __launch_bounds__(256)
void k_cmax(const uint4* __restrict__ z2g, unsigned* __restrict__ kmax,
            unsigned* __restrict__ kmin)
{
  const int wave = threadIdx.x>>6, lane = threadIdx.x&63;
  const int m = lane&15, g = lane>>4;
  const int blk = blockIdx.x;            // 1000 blocks; 250/batch (10 tiles each)
  const int b = blk/250;
  const int ks = wave;
  float mx[8], mn[8];
#pragma unroll
  for (int j=0;j<8;++j){ mx[j]=-1e30f; mn[j]=1e30f; }
#pragma unroll 1
  for (int t=0;t<10;++t){
    int it = blk*10 + t;
    uint4 v = z2g[(size_t)(it*4+ks)*64 + lane];
    unsigned u0=v.x,u1=v.y,u2=v.z,u3=v.w;
    mx[0]=fmaxf(mx[0],uplo(u0)); mn[0]=fminf(mn[0],uplo(u0));
    mx[1]=fmaxf(mx[1],uphi(u0)); mn[1]=fminf(mn[1],uphi(u0));
    mx[2]=fmaxf(mx[2],uplo(u1)); mn[2]=fminf(mn[2],uplo(u1));
    mx[3]=fmaxf(mx[3],uphi(u1)); mn[3]=fminf(mn[3],uphi(u1));
    mx[4]=fmaxf(mx[4],uplo(u2)); mn[4]=fminf(mn[4],uplo(u2));
    mx[5]=fmaxf(mx[5],uphi(u2)); mn[5]=fminf(mn[5],uphi(u2));
    mx[6]=fmaxf(mx[6],uplo(u3)); mn[6]=fminf(mn[6],uplo(u3));
    mx[7]=fmaxf(mx[7],uphi(u3)); mn[7]=fminf(mn[7],uphi(u3));
  }
#pragma unroll
  for (int j=0;j<8;++j){
#pragma unroll
    for (int o=1;o<16;o<<=1){
      mx[j]=fmaxf(mx[j],__shfl_xor(mx[j],o));
      mn[j]=fminf(mn[j],__shfl_xor(mn[j],o));
    }
  }
  if (m==0){
#pragma unroll
    for (int j=0;j<8;++j){
      int c = 32*ks + 8*g + j;
      atomicMax(&kmax[b*CD+c], fenc(mx[j]));
      atomicMin(&kmin[b*CD+c], fenc(mn[j]));
    }
  }
}

// ---------------------------------------------------------------------------
// Phase B: u = z2@(g2*W3top) + gcomb; h2=relu(LN3(u)); w=2*sigmoid(h2@W4).
// Prologue computes gcomb per-block (folded k_global):
//   gs = g2*(g2>=0?zmax:zmin)+be2;  GC = b3 + be2@W3top + gs@W3bot.
// 256 thr, grid 512, 5 strided reps, z prefetch.
// ---------------------------------------------------------------------------
__global__ __launch_bounds__(256)
void k_B(const uint4* __restrict__ z2g, const float* __restrict__ g2,
         const float* __restrict__ be2,
         const float* __restrict__ W3, const float* __restrict__ b3,
         const float* __restrict__ g3, const float* __restrict__ be3,
         const float* __restrict__ W4, const float* __restrict__ masks,
         const unsigned* __restrict__ kmax, const unsigned* __restrict__ kmin,
         unsigned short* __restrict__ mwT, float* __restrict__ denom)
{
  __shared__ uint4 W3F[2048];        // g2 folded into rows
  __shared__ uint2 Pg[32], Pb[32], Pw[32];
  __shared__ float GS[128], BS[128], PART[256], GC[128];

  const int tid = threadIdx.x;
  const int b = blockIdx.x >> 7;               // 128 blocks per batch
  for (int e = tid; e < 2048; e += 256){
    int f = e >> 6, l = e & 63;
    int ks = f >> 3, mto = f & 7;
    int lm = l & 15, lg = l >> 4;
    int ci = 32*ks + 8*lg, co = 16*mto + lm;
    uint4 v;
    v.x = pk2(g2[ci+0]*W3[(ci+0)*CD+co], g2[ci+1]*W3[(ci+1)*CD+co]);
    v.y = pk2(g2[ci+2]*W3[(ci+2)*CD+co], g2[ci+3]*W3[(ci+3)*CD+co]);
    v.z = pk2(g2[ci+4]*W3[(ci+4)*CD+co], g2[ci+5]*W3[(ci+5)*CD+co]);
    v.w = pk2(g2[ci+6]*W3[(ci+6)*CD+co], g2[ci+7]*W3[(ci+7)*CD+co]);
    W3F[e] = v;
  }
  if (tid < 32){
    int t4 = tid*4;
    uint2 v;
    v.x = pk2(g3[t4], g3[t4+1]);  v.y = pk2(g3[t4+2], g3[t4+3]);  Pg[tid] = v;
    v.x = pk2(be3[t4],be3[t4+1]); v.y = pk2(be3[t4+2],be3[t4+3]); Pb[tid] = v;
    v.x = pk2(W4[t4], W4[t4+1]);  v.y = pk2(W4[t4+2], W4[t4+3]);  Pw[tid] = v;
  }
  if (tid < 128){
    float gg = g2[tid];
    float zx = fdec(kmax[b*CD+tid]), zn = fdec(kmin[b*CD+tid]);
    GS[tid] = (gg>=0.f ? gg*zx : gg*zn) + be2[tid];
    BS[tid] = be2[tid];
  }
  __syncthreads();
  {
    int c = tid & 127, half = tid >> 7;
    float accv = 0.f;
    if (half==0){
      for (int k=0;k<128;++k) accv = fmaf(BS[k], W3[k*CD+c], accv);
      accv += b3[c];
    } else {
      for (int k=0;k<128;++k) accv = fmaf(GS[k], W3[(128+k)*CD+c], accv);
    }
    PART[tid] = accv;
  }
  __syncthreads();
  if (tid < 128) GC[tid] = PART[tid] + PART[128+tid];
  __syncthreads();

  const int wave = tid>>6, lane = tid&63;
  const int m = lane&15, g = lane>>4;
  const int wb = (blockIdx.x & 127)*4 + wave;  // 0..511 within batch
  float dacc = 0.f;

  int tb = wb;
  uint4 z0, z1, z2v, z3;
  {
    size_t base = ((size_t)(b*2500+tb)*4)*64 + lane;
    z0 = z2g[base]; z1 = z2g[base+64]; z2v = z2g[base+128]; z3 = z2g[base+192];
  }

#pragma unroll 1
  for (int rep = 0; rep < 5; ++rep){
    if (tb >= 2500) break;
    const int tbn = tb + 512;
    const bool hasn = (rep < 4) && (tbn < 2500);
    uint4 n0, n1, n2, n3;
    if (hasn){
      size_t basen = ((size_t)(b*2500+tbn)*4)*64 + lane;
      n0 = z2g[basen]; n1 = z2g[basen+64]; n2 = z2g[basen+128]; n3 = z2g[basen+192];
    }

    f4_t a3[8];
#pragma unroll
    for (int mt=0;mt<8;++mt) a3[mt]=(f4_t){0.f,0.f,0.f,0.f};
#pragma unroll
    for (int ks=0;ks<4;++ks){
      bf8_t Bf = bc8(ks==0?z0:ks==1?z1:ks==2?z2v:z3);
#pragma unroll
      for (int mto=0;mto<8;++mto)
        a3[mto] = __builtin_amdgcn_mfma_f32_16x16x32_bf16(
                      bc8(W3F[(ks*8+mto)*64+lane]), Bf, a3[mto], 0,0,0);
    }

    float s1=0.f, s2=0.f;
#pragma unroll
    for (int mt=0;mt<8;++mt){
      float4 gcq = *reinterpret_cast<const float4*>(&GC[16*mt+4*g]);
      a3[mt][0]+=gcq.x; a3[mt][1]+=gcq.y; a3[mt][2]+=gcq.z; a3[mt][3]+=gcq.w;
#pragma unroll
      for (int r=0;r<4;++r){ float v=a3[mt][r]; s1+=v; s2=fmaf(v,v,s2); }
    }
    s1 += __shfl_xor(s1,16); s1 += __shfl_xor(s1,32);
    s2 += __shfl_xor(s2,16); s2 += __shfl_xor(s2,32);
    float mu = s1*(1.f/128.f);
    float rs = rsqrtf(fmaxf(s2*(1.f/128.f)-mu*mu,0.f)+1e-5f);

    float U = 0.f;
#pragma unroll
    for (int mt=0;mt<8;++mt){
      uint2 gv = Pg[4*mt+g], bv = Pb[4*mt+g], wv = Pw[4*mt+g];
      float h0 = fmaxf(0.f, fmaf((a3[mt][0]-mu)*rs, uplo(gv.x), uplo(bv.x)));
      float h1 = fmaxf(0.f, fmaf((a3[mt][1]-mu)*rs, uphi(gv.x), uphi(bv.x)));
      float h2 = fmaxf(0.f, fmaf((a3[mt][2]-mu)*rs, uplo(gv.y), uplo(bv.y)));
      float h3 = fmaxf(0.f, fmaf((a3[mt][3]-mu)*rs, uphi(gv.y), uphi(bv.y)));
      U = fmaf(h0, uplo(wv.x), U); U = fmaf(h1, uphi(wv.x), U);
      U = fmaf(h2, uplo(wv.y), U); U = fmaf(h3, uphi(wv.y), U);
    }
    U += __shfl_xor(U,16); U += __shfl_xor(U,32);
    float w = 2.f/(1.f + __expf(-U));
    const int n = tb*16 + m;
    float msk = masks[(size_t)(4*b+g)*NPTS + n];
    mwT[(size_t)(b*4+g)*NPTS + n] = f2bfu(msk*w);
    dacc += msk*w;

    if (hasn){ z0 = n0; z1 = n1; z2v = n2; z3 = n3; }
    tb = tbn;
  }

  dacc += __shfl_xor(dacc,1); dacc += __shfl_xor(dacc,2);
  dacc += __shfl_xor(dacc,4); dacc += __shfl_xor(dacc,8);
  if (m==0) atomicAdd(&denom[b*4+g], dacc);
}

// pooled[b,v,c] = sum_n mw[b,v,n]*feat[b,c,n]  — coalesced VALU reduction.
// grid 2016 = 4 b x 8 cgroup x 63 nchunk(640); block = 16 c-rows x 16 lanes.
__global__ __launch_bounds__(256)
void k_pool(const float* __restrict__ feat, const unsigned short* __restrict__ mwT,
            float* __restrict__ pool_acc)
{
  const int b   = blockIdx.x / 504;
  const int rem = blockIdx.x % 504;
  const int cg  = rem / 63;
  const int nch = rem % 63;
  const int cl  = threadIdx.x >> 4, ln = threadIdx.x & 15;
  const int c   = cg*16 + cl;
  const int n0  = nch*640;
  const float* f = &feat[((size_t)b*CD + c)*NPTS];
  const unsigned short* mw = &mwT[(size_t)b*4*NPTS];
  float a0=0.f, a1=0.f, a2=0.f, a3=0.f;
#pragma unroll
  for (int itr=0; itr<10; ++itr){
    int n = n0 + itr*64 + ln*4;
    if (n < NPTS){
      float4 fv = *reinterpret_cast<const float4*>(&f[n]);
      uint2 m0 = *reinterpret_cast<const uint2*>(&mw[0*NPTS+n]);
      uint2 m1 = *reinterpret_cast<const uint2*>(&mw[1*NPTS+n]);
      uint2 m2 = *reinterpret_cast<const uint2*>(&mw[2*NPTS+n]);
      uint2 m3 = *reinterpret_cast<const uint2*>(&mw[3*NPTS+n]);
      a0 = fmaf(fv.x,uplo(m0.x),a0); a0 = fmaf(fv.y,uphi(m0.x),a0);
      a0 = fmaf(fv.z,uplo(m0.y),a0); a0 = fmaf(fv.w,uphi(m0.y),a0);
      a1 = fmaf(fv.x,uplo(m1.x),a1); a1 = fmaf(fv.y,uphi(m1.x),a1);
      a1 = fmaf(fv.z,uplo(m1.y),a1); a1 = fmaf(fv.w,uphi(m1.y),a1);
      a2 = fmaf(fv.x,uplo(m2.x),a2); a2 = fmaf(fv.y,uphi(m2.x),a2);
      a2 = fmaf(fv.z,uplo(m2.y),a2); a2 = fmaf(fv.w,uphi(m2.y),a2);
      a3 = fmaf(fv.x,uplo(m3.x),a3); a3 = fmaf(fv.y,uphi(m3.x),a3);
      a3 = fmaf(fv.z,uplo(m3.y),a3); a3 = fmaf(fv.w,uphi(m3.y),a3);
    }
  }
#pragma unroll
  for (int o=1;o<16;o<<=1){
    a0 += __shfl_xor(a0,o); a1 += __shfl_xor(a1,o);
    a2 += __shfl_xor(a2,o); a3 += __shfl_xor(a3,o);
  }
  if (ln == 0){
    atomicAdd(&pool_acc[(b*4+0)*CD + c], a0);
    atomicAdd(&pool_acc[(b*4+1)*CD + c], a1);
    atomicAdd(&pool_acc[(b*4+2)*CD + c], a2);
    atomicAdd(&pool_acc[(b*4+3)*CD + c], a3);
  }
}

// out = pool/denom + global_xyz, global decoded inline from kmax/kmin.
__global__ __launch_bounds__(256)
void k_final(const float* __restrict__ pool_acc, const float* __restrict__ denom,
             const unsigned* __restrict__ kmax, const unsigned* __restrict__ kmin,
             const float* __restrict__ g2, const float* __restrict__ be2,
             float* __restrict__ out)
{
  int t = blockIdx.x*256 + threadIdx.x;   // 2048
  int bv = t>>7, c = t&127, b = bv>>2;
  float gg = g2[c];
  float zx = fdec(kmax[b*CD+c]), zn = fdec(kmin[b*CD+c]);
  float gl = (gg>=0.f ? gg*zx : gg*zn) + be2[c];
  out[t] = pool_acc[t]/(denom[bv]+1e-8f) + gl;
}

extern "C" void kernel_launch(void* const* d_in, const int* in_sizes, int n_in,
                              void* d_out, int out_size, void* d_ws,
                              size_t ws_size, hipStream_t stream) {
  const float* xyz  = (const float*)d_in[0];
  const float* feat = (const float*)d_in[1];
  const float* masks= (const float*)d_in[2];
  const float* W1 = (const float*)d_in[3];
  const float* b1 = (const float*)d_in[4];
  const float* g1 = (const float*)d_in[5];
  const float* be1= (const float*)d_in[6];
  const float* W2 = (const float*)d_in[7];
  const float* b2 = (const float*)d_in[8];
  const float* g2 = (const float*)d_in[9];
  const float* be2= (const float*)d_in[10];
  const float* W3 = (const float*)d_in[11];
  const float* b3 = (const float*)d_in[12];
  const float* g3 = (const float*)d_in[13];
  const float* be3= (const float*)d_in[14];
  const float* W4 = (const float*)d_in[15];
  float* out = (float*)d_out;

  char* ws = (char*)d_ws;
  unsigned* kmax    = (unsigned*)ws;                   // 2048 B
  unsigned* kmin    = (unsigned*)(ws + 2048);          // 2048 B
  float*    denom   = (float*)(ws + 4096);             // 64 B
  float*    pool_acc= (float*)(ws + 4352);             // 8192 B
  unsigned short* mwT = (unsigned short*)(ws + 16640); // 1.28 MB
  uint4*    z2g     = (uint4*)(ws + 5136640);          // 40.96 MB

  k_A<<<512, 512, 0, stream>>>(xyz, W1, b1, g1, be1, W2, b2, z2g,
                               kmax, kmin, denom, pool_acc);
  k_cmax<<<1000, 256, 0, stream>>>(z2g, kmax, kmin);
  k_B<<<512, 256, 0, stream>>>(z2g, g2, be2, W3, b3, g3, be3, W4, masks,
                               kmax, kmin, mwT, denom);
  k_pool<<<2016, 256, 0, stream>>>(feat, mwT, pool_acc);
  k_final<<<8, 256, 0, stream>>>(pool_acc, denom, kmax, kmin, g2, be2, out);
}

// Round 12
// 154.199 us; speedup vs baseline: 1.3659x; 1.3659x over previous
//
#include <hip/hip_runtime.h>
#include <stdint.h>

// GeoAwarePooling B=4, N=40000, C=128, V=4.
// xyz is broadcast across views -> per-point MLP runs once over B*N points.
// v12: v10's spill-free k_A loop (256thr, 5 const-indexed reps, NO carried
// state — any extra live regs across the body spills: R6/R8/R11) + v11's
// launch folding (init in k_A blk0, k_global in k_B prologue, k_final decode).

#define NPTS 40000
#define CD   128

typedef __attribute__((ext_vector_type(8))) short bf8_t;
typedef __attribute__((ext_vector_type(4))) float f4_t;

__device__ __forceinline__ unsigned short f2bfu(float f){
  unsigned u = __float_as_uint(f);
  u += 0x7FFFu + ((u>>16)&1u);               // RNE
  return (unsigned short)(u>>16);
}
__device__ __forceinline__ float bfhi_f(float f){   // f rounded to bf16, as f32
  return __uint_as_float(((unsigned)f2bfu(f))<<16);
}
__device__ __forceinline__ unsigned pk2(float a, float b){
  return (unsigned)f2bfu(a) | ((unsigned)f2bfu(b)<<16);
}
__device__ __forceinline__ float uplo(unsigned u){ return __uint_as_float(u<<16); }
__device__ __forceinline__ float uphi(unsigned u){ return __uint_as_float(u & 0xFFFF0000u); }
__device__ __forceinline__ unsigned fenc(float f){  // order-preserving key
  unsigned u = __float_as_uint(f);
  return (u & 0x80000000u) ? ~u : (u | 0x80000000u);
}
__device__ __forceinline__ float fdec(unsigned k){
  return (k & 0x80000000u) ? __uint_as_float(k & 0x7FFFFFFFu) : __uint_as_float(~k);
}
__device__ __forceinline__ bf8_t bc8(uint4 v){ return __builtin_bit_cast(bf8_t, v); }

// ---------------------------------------------------------------------------
// Phase A: y=xyz@W1+b1 (K=32 MFMA, hi/lo split, fp32-exact); h=relu(LN1(y));
// z=(h@W2+b2 normalized, pre-affine) -> global in B-FRAGMENT layout:
// z2g[(it*4+ks)*64+lane]. 256 thr (4 waves), grid 512, 5 const-indexed reps.
// Block 0 also zero-inits the ws accumulators (consumers in later kernels).
// ---------------------------------------------------------------------------
__global__ __launch_bounds__(256)
void k_A(const float* __restrict__ xyz,
         const float* __restrict__ W1, const float* __restrict__ b1,
         const float* __restrict__ g1, const float* __restrict__ be1,
         const float* __restrict__ W2, const float* __restrict__ b2,
         uint4* __restrict__ z2g,
         unsigned* __restrict__ kmax, unsigned* __restrict__ kmin,
         float* __restrict__ denom, float* __restrict__ pool_acc)
{
  __shared__ uint4 W2F[2048];        // 32 KiB  [frag=ks*8+mto][lane]
  __shared__ uint4 A1F[512];         // 8 KiB   [mto][lane]
  __shared__ uint4 Hb4[4][16][16];   // 16 KiB  per-wave transpose tile
  __shared__ uint2 P1u[32], P2u[32], P3u[32];

  const int tid = threadIdx.x;
  if (blockIdx.x == 0){
    if (tid < 16) denom[tid] = 0.f;
    for (int i = tid; i < 512; i += 256){ kmax[i] = 0u; kmin[i] = 0xFFFFFFFFu; }
    for (int i = tid; i < 2048; i += 256) pool_acc[i] = 0.f;
  }
  for (int e = tid; e < 2048; e += 256){
    int f = e >> 6, l = e & 63;
    int ks = f >> 3, mto = f & 7;
    int lm = l & 15, lg = l >> 4;
    int ci = 32*ks + 8*lg, co = 16*mto + lm;
    uint4 v;
    v.x = pk2(W2[(ci+0)*CD+co], W2[(ci+1)*CD+co]);
    v.y = pk2(W2[(ci+2)*CD+co], W2[(ci+3)*CD+co]);
    v.z = pk2(W2[(ci+4)*CD+co], W2[(ci+5)*CD+co]);
    v.w = pk2(W2[(ci+6)*CD+co], W2[(ci+7)*CD+co]);
    W2F[e] = v;
  }
  for (int e = tid; e < 512; e += 256){
    int mto = e >> 6, l = e & 63;
    int lm = l & 15, lg = l >> 4;
    int c = 16*mto + lm;
    float w0=W1[c], w1=W1[CD+c], w2=W1[2*CD+c], bb=b1[c];
    uint4 v = {0u,0u,0u,0u};
    if (lg==0){ v.x=pk2(w0,w1); v.y=pk2(w2,w0); v.z=pk2(w1,w2);
                v.w=pk2(w0-bfhi_f(w0), w1-bfhi_f(w1)); }
    else if (lg==1){ v.x=pk2(w2-bfhi_f(w2), bb); v.y=pk2(bb-bfhi_f(bb),0.f); }
    A1F[e] = v;
  }
  if (tid < 32){
    int t4 = tid*4;
    uint2 v;
    v.x = pk2(g1[t4], g1[t4+1]);  v.y = pk2(g1[t4+2], g1[t4+3]);  P1u[tid] = v;
    v.x = pk2(be1[t4],be1[t4+1]); v.y = pk2(be1[t4+2],be1[t4+3]); P2u[tid] = v;
    v.x = pk2(b2[t4], b2[t4+1]);  v.y = pk2(b2[t4+2], b2[t4+3]);  P3u[tid] = v;
  }
  __syncthreads();

  const int wave = tid>>6, lane = tid&63;
  const int m = lane&15, g = lane>>4;
  const int b  = blockIdx.x >> 7;              // 128 blocks per batch
  const int wb = (blockIdx.x & 127)*4 + wave;  // 0..511 within batch
  const int swz = m & 7;
  const float* xyzb = xyz + (size_t)3*b*NPTS;
  uint2* Hb2 = (uint2*)&Hb4[wave][0][0];

#pragma unroll 1
  for (int rep = 0; rep < 5; ++rep){
    const int tb = wb + rep*512;
    if (tb >= 2500) break;
    const int it = b*2500 + tb;
    const int n = tb*16 + m;
    float px = xyzb[n], py = xyzb[NPTS+n], pz = xyzb[2*NPTS+n];

    uint4 B1u = {0u,0u,0u,0u};
    if (g==0){ B1u.x = pk2(px,py); B1u.y = pk2(pz, px-bfhi_f(px));
               B1u.z = pk2(py-bfhi_f(py), pz-bfhi_f(pz)); B1u.w = pk2(px,py); }
    else if (g==1){ B1u.x = pk2(pz, 1.0f); B1u.y = pk2(1.0f, 0.f); }
    bf8_t B1 = bc8(B1u);

    // GEMM1
    f4_t acc[8];
#pragma unroll
    for (int mt=0;mt<8;++mt)
      acc[mt] = __builtin_amdgcn_mfma_f32_16x16x32_bf16(
                    bc8(A1F[mt*64+lane]), B1, (f4_t){0.f,0.f,0.f,0.f}, 0,0,0);

    // LN1
    float s1=0.f, s2=0.f;
#pragma unroll
    for (int mt=0;mt<8;++mt)
#pragma unroll
      for (int r=0;r<4;++r){ float v=acc[mt][r]; s1+=v; s2=fmaf(v,v,s2); }
    s1 += __shfl_xor(s1,16); s1 += __shfl_xor(s1,32);
    s2 += __shfl_xor(s2,16); s2 += __shfl_xor(s2,32);
    float mu = s1*(1.f/128.f);
    float rs = rsqrtf(fmaxf(s2*(1.f/128.f)-mu*mu,0.f)+1e-5f);

    // affine+relu -> write h pairs into swizzled transpose tile
#pragma unroll
    for (int mt=0;mt<8;++mt){
      uint2 gv = P1u[4*mt+g], bv = P2u[4*mt+g];
      float h0 = fmaxf(0.f, fmaf((acc[mt][0]-mu)*rs, uplo(gv.x), uplo(bv.x)));
      float h1 = fmaxf(0.f, fmaf((acc[mt][1]-mu)*rs, uphi(gv.x), uphi(bv.x)));
      float h2 = fmaxf(0.f, fmaf((acc[mt][2]-mu)*rs, uplo(gv.y), uplo(bv.y)));
      float h3 = fmaxf(0.f, fmaf((acc[mt][3]-mu)*rs, uphi(gv.y), uphi(bv.y)));
      uint2 wv; wv.x = pk2(h0,h1); wv.y = pk2(h2,h3);
      int slot = ((mt>>1)*4 + 2*(mt&1) + (g>>1)) ^ swz;
      Hb2[(m*16 + slot)*2 + (g&1)] = wv;
    }

    // GEMM2: B-frags from transpose tile, A-frags from W2F
    f4_t a2[8];
#pragma unroll
    for (int mt=0;mt<8;++mt) a2[mt]=(f4_t){0.f,0.f,0.f,0.f};
#pragma unroll
    for (int ks=0;ks<4;++ks){
      bf8_t Bf = bc8(Hb4[wave][m][(ks*4+g)^swz]);
#pragma unroll
      for (int mto=0;mto<8;++mto)
        a2[mto] = __builtin_amdgcn_mfma_f32_16x16x32_bf16(
                      bc8(W2F[(ks*8+mto)*64+lane]), Bf, a2[mto], 0,0,0);
    }

    // +b2, LN2
    s1=0.f; s2=0.f;
#pragma unroll
    for (int mt=0;mt<8;++mt){
      uint2 bv = P3u[4*mt+g];
      a2[mt][0]+=uplo(bv.x); a2[mt][1]+=uphi(bv.x);
      a2[mt][2]+=uplo(bv.y); a2[mt][3]+=uphi(bv.y);
#pragma unroll
      for (int r=0;r<4;++r){ float v=a2[mt][r]; s1+=v; s2=fmaf(v,v,s2); }
    }
    s1 += __shfl_xor(s1,16); s1 += __shfl_xor(s1,32);
    s2 += __shfl_xor(s2,16); s2 += __shfl_xor(s2,32);
    mu = s1*(1.f/128.f);
    rs = rsqrtf(fmaxf(s2*(1.f/128.f)-mu*mu,0.f)+1e-5f);

    // z pairs -> transpose tile -> read frags -> coalesced global store
#pragma unroll
    for (int mt=0;mt<8;++mt){
      float z0=(a2[mt][0]-mu)*rs, z1=(a2[mt][1]-mu)*rs;
      float z2v=(a2[mt][2]-mu)*rs, z3=(a2[mt][3]-mu)*rs;
      uint2 wv; wv.x=pk2(z0,z1); wv.y=pk2(z2v,z3);
      int slot = ((mt>>1)*4 + 2*(mt&1) + (g>>1)) ^ swz;
      Hb2[(m*16 + slot)*2 + (g&1)] = wv;
    }
#pragma unroll
    for (int ks=0;ks<4;++ks){
      uint4 frag = Hb4[wave][m][(ks*4+g)^swz];
      z2g[(size_t)(it*4+ks)*64 + lane] = frag;
    }
  }
}

// per-channel max/min scan of z2 (frag layout). wave w handles k-slice w.
// 1000 blocks x 10 tiles.
__global__ __launch_bounds__(256)
void k_cmax(const uint4* __restrict__ z2g, unsigned* __restrict__ kmax,
            unsigned* __restrict__ kmin)
{
  const int wave = threadIdx.x>>6, lane = threadIdx.x&63;
  const int m = lane&15, g = lane>>4;
  const int blk = blockIdx.x;            // 1000 blocks; 250/batch (10 tiles each)
  const int b = blk/250;
  const int ks = wave;
  float mx[8], mn[8];
#pragma unroll
  for (int j=0;j<8;++j){ mx[j]=-1e30f; mn[j]=1e30f; }
#pragma unroll 1
  for (int t=0;t<10;++t){
    int it = blk*10 + t;
    uint4 v = z2g[(size_t)(it*4+ks)*64 + lane];
    unsigned u0=v.x,u1=v.y,u2=v.z,u3=v.w;
    mx[0]=fmaxf(mx[0],uplo(u0)); mn[0]=fminf(mn[0],uplo(u0));
    mx[1]=fmaxf(mx[1],uphi(u0)); mn[1]=fminf(mn[1],uphi(u0));
    mx[2]=fmaxf(mx[2],uplo(u1)); mn[2]=fminf(mn[2],uplo(u1));
    mx[3]=fmaxf(mx[3],uphi(u1)); mn[3]=fminf(mn[3],uphi(u1));
    mx[4]=fmaxf(mx[4],uplo(u2)); mn[4]=fminf(mn[4],uplo(u2));
    mx[5]=fmaxf(mx[5],uphi(u2)); mn[5]=fminf(mn[5],uphi(u2));
    mx[6]=fmaxf(mx[6],uplo(u3)); mn[6]=fminf(mn[6],uplo(u3));
    mx[7]=fmaxf(mx[7],uphi(u3)); mn[7]=fminf(mn[7],uphi(u3));
  }
#pragma unroll
  for (int j=0;j<8;++j){
#pragma unroll
    for (int o=1;o<16;o<<=1){
      mx[j]=fmaxf(mx[j],__shfl_xor(mx[j],o));
      mn[j]=fminf(mn[j],__shfl_xor(mn[j],o));
    }
  }
  if (m==0){
#pragma unroll
    for (int j=0;j<8;++j){
      int c = 32*ks + 8*g + j;
      atomicMax(&kmax[b*CD+c], fenc(mx[j]));
      atomicMin(&kmin[b*CD+c], fenc(mn[j]));
    }
  }
}

// ---------------------------------------------------------------------------
// Phase B: u = z2@(g2*W3top) + gcomb; h2=relu(LN3(u)); w=2*sigmoid(h2@W4).
// Prologue computes gcomb per-block (folded k_global):
//   gs = g2*(g2>=0?zmax:zmin)+be2;  GC = b3 + be2@W3top + gs@W3bot.
// 256 thr, grid 512, 5 strided reps, z prefetch.
// ---------------------------------------------------------------------------
__global__ __launch_bounds__(256)
void k_B(const uint4* __restrict__ z2g, const float* __restrict__ g2,
         const float* __restrict__ be2,
         const float* __restrict__ W3, const float* __restrict__ b3,
         const float* __restrict__ g3, const float* __restrict__ be3,
         const float* __restrict__ W4, const float* __restrict__ masks,
         const unsigned* __restrict__ kmax, const unsigned* __restrict__ kmin,
         unsigned short* __restrict__ mwT, float* __restrict__ denom)
{
  __shared__ uint4 W3F[2048];        // g2 folded into rows
  __shared__ uint2 Pg[32], Pb[32], Pw[32];
  __shared__ float GS[128], BS[128], PART[256], GC[128];

  const int tid = threadIdx.x;
  const int b = blockIdx.x >> 7;               // 128 blocks per batch
  for (int e = tid; e < 2048; e += 256){
    int f = e >> 6, l = e & 63;
    int ks = f >> 3, mto = f & 7;
    int lm = l & 15, lg = l >> 4;
    int ci = 32*ks + 8*lg, co = 16*mto + lm;
    uint4 v;
    v.x = pk2(g2[ci+0]*W3[(ci+0)*CD+co], g2[ci+1]*W3[(ci+1)*CD+co]);
    v.y = pk2(g2[ci+2]*W3[(ci+2)*CD+co], g2[ci+3]*W3[(ci+3)*CD+co]);
    v.z = pk2(g2[ci+4]*W3[(ci+4)*CD+co], g2[ci+5]*W3[(ci+5)*CD+co]);
    v.w = pk2(g2[ci+6]*W3[(ci+6)*CD+co], g2[ci+7]*W3[(ci+7)*CD+co]);
    W3F[e] = v;
  }
  if (tid < 32){
    int t4 = tid*4;
    uint2 v;
    v.x = pk2(g3[t4], g3[t4+1]);  v.y = pk2(g3[t4+2], g3[t4+3]);  Pg[tid] = v;
    v.x = pk2(be3[t4],be3[t4+1]); v.y = pk2(be3[t4+2],be3[t4+3]); Pb[tid] = v;
    v.x = pk2(W4[t4], W4[t4+1]);  v.y = pk2(W4[t4+2], W4[t4+3]);  Pw[tid] = v;
  }
  if (tid < 128){
    float gg = g2[tid];
    float zx = fdec(kmax[b*CD+tid]), zn = fdec(kmin[b*CD+tid]);
    GS[tid] = (gg>=0.f ? gg*zx : gg*zn) + be2[tid];
    BS[tid] = be2[tid];
  }
  __syncthreads();
  {
    int c = tid & 127, half = tid >> 7;
    float accv = 0.f;
    if (half==0){
      for (int k=0;k<128;++k) accv = fmaf(BS[k], W3[k*CD+c], accv);
      accv += b3[c];
    } else {
      for (int k=0;k<128;++k) accv = fmaf(GS[k], W3[(128+k)*CD+c], accv);
    }
    PART[tid] = accv;
  }
  __syncthreads();
  if (tid < 128) GC[tid] = PART[tid] + PART[128+tid];
  __syncthreads();

  const int wave = tid>>6, lane = tid&63;
  const int m = lane&15, g = lane>>4;
  const int wb = (blockIdx.x & 127)*4 + wave;  // 0..511 within batch
  float dacc = 0.f;

  int tb = wb;
  uint4 z0, z1, z2v, z3;
  {
    size_t base = ((size_t)(b*2500+tb)*4)*64 + lane;
    z0 = z2g[base]; z1 = z2g[base+64]; z2v = z2g[base+128]; z3 = z2g[base+192];
  }

#pragma unroll 1
  for (int rep = 0; rep < 5; ++rep){
    if (tb >= 2500) break;
    const int tbn = tb + 512;
    const bool hasn = (rep < 4) && (tbn < 2500);
    uint4 n0, n1, n2, n3;
    if (hasn){
      size_t basen = ((size_t)(b*2500+tbn)*4)*64 + lane;
      n0 = z2g[basen]; n1 = z2g[basen+64]; n2 = z2g[basen+128]; n3 = z2g[basen+192];
    }

    f4_t a3[8];
#pragma unroll
    for (int mt=0;mt<8;++mt) a3[mt]=(f4_t){0.f,0.f,0.f,0.f};
#pragma unroll
    for (int ks=0;ks<4;++ks){
      bf8_t Bf = bc8(ks==0?z0:ks==1?z1:ks==2?z2v:z3);
#pragma unroll
      for (int mto=0;mto<8;++mto)
        a3[mto] = __builtin_amdgcn_mfma_f32_16x16x32_bf16(
                      bc8(W3F[(ks*8+mto)*64+lane]), Bf, a3[mto], 0,0,0);
    }

    float s1=0.f, s2=0.f;
#pragma unroll
    for (int mt=0;mt<8;++mt){
      float4 gcq = *reinterpret_cast<const float4*>(&GC[16*mt+4*g]);
      a3[mt][0]+=gcq.x; a3[mt][1]+=gcq.y; a3[mt][2]+=gcq.z; a3[mt][3]+=gcq.w;
#pragma unroll
      for (int r=0;r<4;++r){ float v=a3[mt][r]; s1+=v; s2=fmaf(v,v,s2); }
    }
    s1 += __shfl_xor(s1,16); s1 += __shfl_xor(s1,32);
    s2 += __shfl_xor(s2,16); s2 += __shfl_xor(s2,32);
    float mu = s1*(1.f/128.f);
    float rs = rsqrtf(fmaxf(s2*(1.f/128.f)-mu*mu,0.f)+1e-5f);

    float U = 0.f;
#pragma unroll
    for (int mt=0;mt<8;++mt){
      uint2 gv = Pg[4*mt+g], bv = Pb[4*mt+g], wv = Pw[4*mt+g];
      float h0 = fmaxf(0.f, fmaf((a3[mt][0]-mu)*rs, uplo(gv.x), uplo(bv.x)));
      float h1 = fmaxf(0.f, fmaf((a3[mt][1]-mu)*rs, uphi(gv.x), uphi(bv.x)));
      float h2 = fmaxf(0.f, fmaf((a3[mt][2]-mu)*rs, uplo(gv.y), uplo(bv.y)));
      float h3 = fmaxf(0.f, fmaf((a3[mt][3]-mu)*rs, uphi(gv.y), uphi(bv.y)));
      U = fmaf(h0, uplo(wv.x), U); U = fmaf(h1, uphi(wv.x), U);
      U = fmaf(h2, uplo(wv.y), U); U = fmaf(h3, uphi(wv.y), U);
    }
    U += __shfl_xor(U,16); U += __shfl_xor(U,32);
    float w = 2.f/(1.f + __expf(-U));
    const int n = tb*16 + m;
    float msk = masks[(size_t)(4*b+g)*NPTS + n];
    mwT[(size_t)(b*4+g)*NPTS + n] = f2bfu(msk*w);
    dacc += msk*w;

    if (hasn){ z0 = n0; z1 = n1; z2v = n2; z3 = n3; }
    tb = tbn;
  }

  dacc += __shfl_xor(dacc,1); dacc += __shfl_xor(dacc,2);
  dacc += __shfl_xor(dacc,4); dacc += __shfl_xor(dacc,8);
  if (m==0) atomicAdd(&denom[b*4+g], dacc);
}

// pooled[b,v,c] = sum_n mw[b,v,n]*feat[b,c,n]  — coalesced VALU reduction.
// grid 2016 = 4 b x 8 cgroup x 63 nchunk(640); block = 16 c-rows x 16 lanes.
__global__ __launch_bounds__(256)
void k_pool(const float* __restrict__ feat, const unsigned short* __restrict__ mwT,
            float* __restrict__ pool_acc)
{
  const int b   = blockIdx.x / 504;
  const int rem = blockIdx.x % 504;
  const int cg  = rem / 63;
  const int nch = rem % 63;
  const int cl  = threadIdx.x >> 4, ln = threadIdx.x & 15;
  const int c   = cg*16 + cl;
  const int n0  = nch*640;
  const float* f = &feat[((size_t)b*CD + c)*NPTS];
  const unsigned short* mw = &mwT[(size_t)b*4*NPTS];
  float a0=0.f, a1=0.f, a2=0.f, a3=0.f;
#pragma unroll
  for (int itr=0; itr<10; ++itr){
    int n = n0 + itr*64 + ln*4;
    if (n < NPTS){
      float4 fv = *reinterpret_cast<const float4*>(&f[n]);
      uint2 m0 = *reinterpret_cast<const uint2*>(&mw[0*NPTS+n]);
      uint2 m1 = *reinterpret_cast<const uint2*>(&mw[1*NPTS+n]);
      uint2 m2 = *reinterpret_cast<const uint2*>(&mw[2*NPTS+n]);
      uint2 m3 = *reinterpret_cast<const uint2*>(&mw[3*NPTS+n]);
      a0 = fmaf(fv.x,uplo(m0.x),a0); a0 = fmaf(fv.y,uphi(m0.x),a0);
      a0 = fmaf(fv.z,uplo(m0.y),a0); a0 = fmaf(fv.w,uphi(m0.y),a0);
      a1 = fmaf(fv.x,uplo(m1.x),a1); a1 = fmaf(fv.y,uphi(m1.x),a1);
      a1 = fmaf(fv.z,uplo(m1.y),a1); a1 = fmaf(fv.w,uphi(m1.y),a1);
      a2 = fmaf(fv.x,uplo(m2.x),a2); a2 = fmaf(fv.y,uphi(m2.x),a2);
      a2 = fmaf(fv.z,uplo(m2.y),a2); a2 = fmaf(fv.w,uphi(m2.y),a2);
      a3 = fmaf(fv.x,uplo(m3.x),a3); a3 = fmaf(fv.y,uphi(m3.x),a3);
      a3 = fmaf(fv.z,uplo(m3.y),a3); a3 = fmaf(fv.w,uphi(m3.y),a3);
    }
  }
#pragma unroll
  for (int o=1;o<16;o<<=1){
    a0 += __shfl_xor(a0,o); a1 += __shfl_xor(a1,o);
    a2 += __shfl_xor(a2,o); a3 += __shfl_xor(a3,o);
  }
  if (ln == 0){
    atomicAdd(&pool_acc[(b*4+0)*CD + c], a0);
    atomicAdd(&pool_acc[(b*4+1)*CD + c], a1);
    atomicAdd(&pool_acc[(b*4+2)*CD + c], a2);
    atomicAdd(&pool_acc[(b*4+3)*CD + c], a3);
  }
}

// out = pool/denom + global_xyz, global decoded inline from kmax/kmin.
__global__ __launch_bounds__(256)
void k_final(const float* __restrict__ pool_acc, const float* __restrict__ denom,
             const unsigned* __restrict__ kmax, const unsigned* __restrict__ kmin,
             const float* __restrict__ g2, const float* __restrict__ be2,
             float* __restrict__ out)
{
  int t = blockIdx.x*256 + threadIdx.x;   // 2048
  int bv = t>>7, c = t&127, b = bv>>2;
  float gg = g2[c];
  float zx = fdec(kmax[b*CD+c]), zn = fdec(kmin[b*CD+c]);
  float gl = (gg>=0.f ? gg*zx : gg*zn) + be2[c];
  out[t] = pool_acc[t]/(denom[bv]+1e-8f) + gl;
}

extern "C" void kernel_launch(void* const* d_in, const int* in_sizes, int n_in,
                              void* d_out, int out_size, void* d_ws,
                              size_t ws_size, hipStream_t stream) {
  const float* xyz  = (const float*)d_in[0];
  const float* feat = (const float*)d_in[1];
  const float* masks= (const float*)d_in[2];
  const float* W1 = (const float*)d_in[3];
  const float* b1 = (const float*)d_in[4];
  const float* g1 = (const float*)d_in[5];
  const float* be1= (const float*)d_in[6];
  const float* W2 = (const float*)d_in[7];
  const float* b2 = (const float*)d_in[8];
  const float* g2 = (const float*)d_in[9];
  const float* be2= (const float*)d_in[10];
  const float* W3 = (const float*)d_in[11];
  const float* b3 = (const float*)d_in[12];
  const float* g3 = (const float*)d_in[13];
  const float* be3= (const float*)d_in[14];
  const float* W4 = (const float*)d_in[15];
  float* out = (float*)d_out;

  char* ws = (char*)d_ws;
  unsigned* kmax    = (unsigned*)ws;                   // 2048 B
  unsigned* kmin    = (unsigned*)(ws + 2048);          // 2048 B
  float*    denom   = (float*)(ws + 4096);             // 64 B
  float*    pool_acc= (float*)(ws + 4352);             // 8192 B
  unsigned short* mwT = (unsigned short*)(ws + 16640); // 1.28 MB
  uint4*    z2g     = (uint4*)(ws + 5136640);          // 40.96 MB

  k_A<<<512, 256, 0, stream>>>(xyz, W1, b1, g1, be1, W2, b2, z2g,
                               kmax, kmin, denom, pool_acc);
  k_cmax<<<1000, 256, 0, stream>>>(z2g, kmax, kmin);
  k_B<<<512, 256, 0, stream>>>(z2g, g2, be2, W3, b3, g3, be3, W4, masks,
                               kmax, kmin, mwT, denom);
  k_pool<<<2016, 256, 0, stream>>>(feat, mwT, pool_acc);
  k_final<<<8, 256, 0, stream>>>(pool_acc, denom, kmax, kmin, g2, be2, out);
}

// Round 13
// 110.302 us; speedup vs baseline: 1.9095x; 1.3980x over previous
//
#include <hip/hip_runtime.h>
#include <stdint.h>

// GeoAwarePooling B=4, N=40000, C=128, V=4.
// xyz is broadcast across views -> per-point MLP runs once over B*N points.
// v13: atomic-free two-stage max/min (k_cpart partials + k_cred reduce, with
// the global/gcomb matvec folded into k_cred); k_B reverted to the measured
// low-VGPR R7 body (VGPR 44) at 4 blocks/CU. k_A unchanged (spill-free).

#define NPTS 40000
#define CD   128

typedef __attribute__((ext_vector_type(8))) short bf8_t;
typedef __attribute__((ext_vector_type(4))) float f4_t;

__device__ __forceinline__ unsigned short f2bfu(float f){
  unsigned u = __float_as_uint(f);
  u += 0x7FFFu + ((u>>16)&1u);               // RNE
  return (unsigned short)(u>>16);
}
__device__ __forceinline__ float bfhi_f(float f){   // f rounded to bf16, as f32
  return __uint_as_float(((unsigned)f2bfu(f))<<16);
}
__device__ __forceinline__ unsigned pk2(float a, float b){
  return (unsigned)f2bfu(a) | ((unsigned)f2bfu(b)<<16);
}
__device__ __forceinline__ float uplo(unsigned u){ return __uint_as_float(u<<16); }
__device__ __forceinline__ float uphi(unsigned u){ return __uint_as_float(u & 0xFFFF0000u); }
__device__ __forceinline__ unsigned fenc(float f){  // order-preserving key
  unsigned u = __float_as_uint(f);
  return (u & 0x80000000u) ? ~u : (u | 0x80000000u);
}
__device__ __forceinline__ float fdec(unsigned k){
  return (k & 0x80000000u) ? __uint_as_float(k & 0x7FFFFFFFu) : __uint_as_float(~k);
}
__device__ __forceinline__ bf8_t bc8(uint4 v){ return __builtin_bit_cast(bf8_t, v); }

// ---------------------------------------------------------------------------
// Phase A: y=xyz@W1+b1 (K=32 MFMA, hi/lo split, fp32-exact); h=relu(LN1(y));
// z=(h@W2+b2 normalized, pre-affine) -> global in B-FRAGMENT layout:
// z2g[(it*4+ks)*64+lane]. 256 thr (4 waves), grid 512, 5 const-indexed reps.
// NO carried state across the body (spills otherwise: R6/R8/R11).
// Block 0 zero-inits denom/pool_acc (consumers are in later kernels).
// ---------------------------------------------------------------------------
__global__ __launch_bounds__(256)
void k_A(const float* __restrict__ xyz,
         const float* __restrict__ W1, const float* __restrict__ b1,
         const float* __restrict__ g1, const float* __restrict__ be1,
         const float* __restrict__ W2, const float* __restrict__ b2,
         uint4* __restrict__ z2g,
         float* __restrict__ denom, float* __restrict__ pool_acc)
{
  __shared__ uint4 W2F[2048];        // 32 KiB  [frag=ks*8+mto][lane]
  __shared__ uint4 A1F[512];         // 8 KiB   [mto][lane]
  __shared__ uint4 Hb4[4][16][16];   // 16 KiB  per-wave transpose tile
  __shared__ uint2 P1u[32], P2u[32], P3u[32];

  const int tid = threadIdx.x;
  if (blockIdx.x == 0){
    if (tid < 16) denom[tid] = 0.f;
    for (int i = tid; i < 2048; i += 256) pool_acc[i] = 0.f;
  }
  for (int e = tid; e < 2048; e += 256){
    int f = e >> 6, l = e & 63;
    int ks = f >> 3, mto = f & 7;
    int lm = l & 15, lg = l >> 4;
    int ci = 32*ks + 8*lg, co = 16*mto + lm;
    uint4 v;
    v.x = pk2(W2[(ci+0)*CD+co], W2[(ci+1)*CD+co]);
    v.y = pk2(W2[(ci+2)*CD+co], W2[(ci+3)*CD+co]);
    v.z = pk2(W2[(ci+4)*CD+co], W2[(ci+5)*CD+co]);
    v.w = pk2(W2[(ci+6)*CD+co], W2[(ci+7)*CD+co]);
    W2F[e] = v;
  }
  for (int e = tid; e < 512; e += 256){
    int mto = e >> 6, l = e & 63;
    int lm = l & 15, lg = l >> 4;
    int c = 16*mto + lm;
    float w0=W1[c], w1=W1[CD+c], w2=W1[2*CD+c], bb=b1[c];
    uint4 v = {0u,0u,0u,0u};
    if (lg==0){ v.x=pk2(w0,w1); v.y=pk2(w2,w0); v.z=pk2(w1,w2);
                v.w=pk2(w0-bfhi_f(w0), w1-bfhi_f(w1)); }
    else if (lg==1){ v.x=pk2(w2-bfhi_f(w2), bb); v.y=pk2(bb-bfhi_f(bb),0.f); }
    A1F[e] = v;
  }
  if (tid < 32){
    int t4 = tid*4;
    uint2 v;
    v.x = pk2(g1[t4], g1[t4+1]);  v.y = pk2(g1[t4+2], g1[t4+3]);  P1u[tid] = v;
    v.x = pk2(be1[t4],be1[t4+1]); v.y = pk2(be1[t4+2],be1[t4+3]); P2u[tid] = v;
    v.x = pk2(b2[t4], b2[t4+1]);  v.y = pk2(b2[t4+2], b2[t4+3]);  P3u[tid] = v;
  }
  __syncthreads();

  const int wave = tid>>6, lane = tid&63;
  const int m = lane&15, g = lane>>4;
  const int b  = blockIdx.x >> 7;              // 128 blocks per batch
  const int wb = (blockIdx.x & 127)*4 + wave;  // 0..511 within batch
  const int swz = m & 7;
  const float* xyzb = xyz + (size_t)3*b*NPTS;
  uint2* Hb2 = (uint2*)&Hb4[wave][0][0];

#pragma unroll 1
  for (int rep = 0; rep < 5; ++rep){
    const int tb = wb + rep*512;
    if (tb >= 2500) break;
    const int it = b*2500 + tb;
    const int n = tb*16 + m;
    float px = xyzb[n], py = xyzb[NPTS+n], pz = xyzb[2*NPTS+n];

    uint4 B1u = {0u,0u,0u,0u};
    if (g==0){ B1u.x = pk2(px,py); B1u.y = pk2(pz, px-bfhi_f(px));
               B1u.z = pk2(py-bfhi_f(py), pz-bfhi_f(pz)); B1u.w = pk2(px,py); }
    else if (g==1){ B1u.x = pk2(pz, 1.0f); B1u.y = pk2(1.0f, 0.f); }
    bf8_t B1 = bc8(B1u);

    // GEMM1
    f4_t acc[8];
#pragma unroll
    for (int mt=0;mt<8;++mt)
      acc[mt] = __builtin_amdgcn_mfma_f32_16x16x32_bf16(
                    bc8(A1F[mt*64+lane]), B1, (f4_t){0.f,0.f,0.f,0.f}, 0,0,0);

    // LN1
    float s1=0.f, s2=0.f;
#pragma unroll
    for (int mt=0;mt<8;++mt)
#pragma unroll
      for (int r=0;r<4;++r){ float v=acc[mt][r]; s1+=v; s2=fmaf(v,v,s2); }
    s1 += __shfl_xor(s1,16); s1 += __shfl_xor(s1,32);
    s2 += __shfl_xor(s2,16); s2 += __shfl_xor(s2,32);
    float mu = s1*(1.f/128.f);
    float rs = rsqrtf(fmaxf(s2*(1.f/128.f)-mu*mu,0.f)+1e-5f);

    // affine+relu -> write h pairs into swizzled transpose tile
#pragma unroll
    for (int mt=0;mt<8;++mt){
      uint2 gv = P1u[4*mt+g], bv = P2u[4*mt+g];
      float h0 = fmaxf(0.f, fmaf((acc[mt][0]-mu)*rs, uplo(gv.x), uplo(bv.x)));
      float h1 = fmaxf(0.f, fmaf((acc[mt][1]-mu)*rs, uphi(gv.x), uphi(bv.x)));
      float h2 = fmaxf(0.f, fmaf((acc[mt][2]-mu)*rs, uplo(gv.y), uplo(bv.y)));
      float h3 = fmaxf(0.f, fmaf((acc[mt][3]-mu)*rs, uphi(gv.y), uphi(bv.y)));
      uint2 wv; wv.x = pk2(h0,h1); wv.y = pk2(h2,h3);
      int slot = ((mt>>1)*4 + 2*(mt&1) + (g>>1)) ^ swz;
      Hb2[(m*16 + slot)*2 + (g&1)] = wv;
    }

    // GEMM2: B-frags from transpose tile, A-frags from W2F
    f4_t a2[8];
#pragma unroll
    for (int mt=0;mt<8;++mt) a2[mt]=(f4_t){0.f,0.f,0.f,0.f};
#pragma unroll
    for (int ks=0;ks<4;++ks){
      bf8_t Bf = bc8(Hb4[wave][m][(ks*4+g)^swz]);
#pragma unroll
      for (int mto=0;mto<8;++mto)
        a2[mto] = __builtin_amdgcn_mfma_f32_16x16x32_bf16(
                      bc8(W2F[(ks*8+mto)*64+lane]), Bf, a2[mto], 0,0,0);
    }

    // +b2, LN2
    s1=0.f; s2=0.f;
#pragma unroll
    for (int mt=0;mt<8;++mt){
      uint2 bv = P3u[4*mt+g];
      a2[mt][0]+=uplo(bv.x); a2[mt][1]+=uphi(bv.x);
      a2[mt][2]+=uplo(bv.y); a2[mt][3]+=uphi(bv.y);
#pragma unroll
      for (int r=0;r<4;++r){ float v=a2[mt][r]; s1+=v; s2=fmaf(v,v,s2); }
    }
    s1 += __shfl_xor(s1,16); s1 += __shfl_xor(s1,32);
    s2 += __shfl_xor(s2,16); s2 += __shfl_xor(s2,32);
    mu = s1*(1.f/128.f);
    rs = rsqrtf(fmaxf(s2*(1.f/128.f)-mu*mu,0.f)+1e-5f);

    // z pairs -> transpose tile -> read frags -> coalesced global store
#pragma unroll
    for (int mt=0;mt<8;++mt){
      float z0=(a2[mt][0]-mu)*rs, z1=(a2[mt][1]-mu)*rs;
      float z2v=(a2[mt][2]-mu)*rs, z3=(a2[mt][3]-mu)*rs;
      uint2 wv; wv.x=pk2(z0,z1); wv.y=pk2(z2v,z3);
      int slot = ((mt>>1)*4 + 2*(mt&1) + (g>>1)) ^ swz;
      Hb2[(m*16 + slot)*2 + (g&1)] = wv;
    }
#pragma unroll
    for (int ks=0;ks<4;++ks){
      uint4 frag = Hb4[wave][m][(ks*4+g)^swz];
      z2g[(size_t)(it*4+ks)*64 + lane] = frag;
    }
  }
}

__device__ __forceinline__ void upd8(uint4 v, float mx[8], float mn[8]){
  mx[0]=fmaxf(mx[0],uplo(v.x)); mn[0]=fminf(mn[0],uplo(v.x));
  mx[1]=fmaxf(mx[1],uphi(v.x)); mn[1]=fminf(mn[1],uphi(v.x));
  mx[2]=fmaxf(mx[2],uplo(v.y)); mn[2]=fminf(mn[2],uplo(v.y));
  mx[3]=fmaxf(mx[3],uphi(v.y)); mn[3]=fminf(mn[3],uphi(v.y));
  mx[4]=fmaxf(mx[4],uplo(v.z)); mn[4]=fminf(mn[4],uplo(v.z));
  mx[5]=fmaxf(mx[5],uphi(v.z)); mn[5]=fminf(mn[5],uphi(v.z));
  mx[6]=fmaxf(mx[6],uplo(v.w)); mn[6]=fminf(mn[6],uplo(v.w));
  mx[7]=fmaxf(mx[7],uphi(v.w)); mn[7]=fminf(mn[7],uphi(v.w));
}

// Stage 1: per-block partial max/min of z2 (frag layout), ZERO atomics.
// 500 blocks = 4 batches x 125; each block scans 20 tiles (4-unrolled loads)
// and stores fenc-encoded partials: pmax[b][125][128], pmin[b][125][128].
__global__ __launch_bounds__(256)
void k_cpart(const uint4* __restrict__ z2g,
             unsigned* __restrict__ pmax, unsigned* __restrict__ pmin)
{
  const int wave = threadIdx.x>>6, lane = threadIdx.x&63;
  const int m = lane&15, g = lane>>4;
  const int blk = blockIdx.x;
  const int b = blk/125, ib = blk%125;
  const int ks = wave;
  float mx[8], mn[8];
#pragma unroll
  for (int j=0;j<8;++j){ mx[j]=-1e30f; mn[j]=1e30f; }
  const uint4* base = z2g + (((size_t)(b*2500 + ib*20))*4 + ks)*64 + lane;
#pragma unroll 1
  for (int t=0;t<20;t+=4){
    uint4 v0 = base[(size_t)(t+0)*256];
    uint4 v1 = base[(size_t)(t+1)*256];
    uint4 v2 = base[(size_t)(t+2)*256];
    uint4 v3 = base[(size_t)(t+3)*256];
    upd8(v0, mx, mn); upd8(v1, mx, mn); upd8(v2, mx, mn); upd8(v3, mx, mn);
  }
#pragma unroll
  for (int j=0;j<8;++j){
#pragma unroll
    for (int o=1;o<16;o<<=1){
      mx[j]=fmaxf(mx[j],__shfl_xor(mx[j],o));
      mn[j]=fminf(mn[j],__shfl_xor(mn[j],o));
    }
  }
  if (m==0){
    size_t row = ((size_t)b*125 + ib)*128 + 32*ks + 8*g;
#pragma unroll
    for (int j=0;j<8;++j){
      pmax[row+j] = fenc(mx[j]);
      pmin[row+j] = fenc(mn[j]);
    }
  }
}

// Stage 2: reduce 125 partials/channel -> global_xyz; then (old k_global)
// gcomb = b3 + be2@W3top + global@W3bot. 4 blocks (one per batch).
__global__ __launch_bounds__(256)
void k_cred(const unsigned* __restrict__ pmax, const unsigned* __restrict__ pmin,
            const float* __restrict__ g2, const float* __restrict__ be2,
            const float* __restrict__ W3, const float* __restrict__ b3,
            float* __restrict__ globalv, float* __restrict__ gcomb)
{
  __shared__ float ZX[128], ZN[128], GS[128], BS[128], PART[256];
  const int b = blockIdx.x, tid = threadIdx.x;
  {
    const int c = tid & 127;
    if (tid < 128){
      unsigned k = 0u;
      const unsigned* p = pmax + (size_t)b*125*128 + c;
#pragma unroll 5
      for (int i=0;i<125;++i) k = max(k, p[(size_t)i*128]);
      ZX[c] = fdec(k);
    } else {
      unsigned k = 0xFFFFFFFFu;
      const unsigned* p = pmin + (size_t)b*125*128 + c;
#pragma unroll 5
      for (int i=0;i<125;++i) k = min(k, p[(size_t)i*128]);
      ZN[c] = fdec(k);
    }
  }
  __syncthreads();
  if (tid < 128){
    float gg = g2[tid];
    float gl = (gg>=0.f ? gg*ZX[tid] : gg*ZN[tid]) + be2[tid];
    GS[tid] = gl;
    globalv[b*CD+tid] = gl;
    BS[tid] = be2[tid];
  }
  __syncthreads();
  {
    int c = tid & 127, half = tid >> 7;
    float accv = 0.f;
    if (half==0){
      for (int k=0;k<128;++k) accv = fmaf(BS[k], W3[k*CD+c], accv);
      accv += b3[c];
    } else {
      for (int k=0;k<128;++k) accv = fmaf(GS[k], W3[(128+k)*CD+c], accv);
    }
    PART[tid] = accv;
  }
  __syncthreads();
  if (tid < 128) gcomb[b*CD+tid] = PART[tid] + PART[128+tid];
}

// ---------------------------------------------------------------------------
// Phase B: u = z2@(g2*W3top) + gcomb; h2=relu(LN3(u)); w=2*sigmoid(h2@W4).
// R7's low-VGPR body (direct just-in-time z loads, precomputed gcomb) at
// 256 thr, grid 1280 (4 blocks/CU by LDS -> 16 waves/CU), 2 strided reps.
// Block-LDS denom pre-reduce (1 atomic set per block).
// ---------------------------------------------------------------------------
__global__ __launch_bounds__(256)
void k_B(const uint4* __restrict__ z2g, const float* __restrict__ g2,
         const float* __restrict__ W3, const float* __restrict__ g3,
         const float* __restrict__ be3, const float* __restrict__ W4,
         const float* __restrict__ masks, const float* __restrict__ gcomb,
         unsigned short* __restrict__ mwT, float* __restrict__ denom)
{
  __shared__ uint4 W3F[2048];        // 32 KiB, g2 folded into rows
  __shared__ uint2 Pg[32], Pb[32], Pw[32];
  __shared__ float GC[128];
  __shared__ float DEN[16];

  const int tid = threadIdx.x;
  const int b = blockIdx.x / 320;              // 320 blocks per batch
  for (int e = tid; e < 2048; e += 256){
    int f = e >> 6, l = e & 63;
    int ks = f >> 3, mto = f & 7;
    int lm = l & 15, lg = l >> 4;
    int ci = 32*ks + 8*lg, co = 16*mto + lm;
    uint4 v;
    v.x = pk2(g2[ci+0]*W3[(ci+0)*CD+co], g2[ci+1]*W3[(ci+1)*CD+co]);
    v.y = pk2(g2[ci+2]*W3[(ci+2)*CD+co], g2[ci+3]*W3[(ci+3)*CD+co]);
    v.z = pk2(g2[ci+4]*W3[(ci+4)*CD+co], g2[ci+5]*W3[(ci+5)*CD+co]);
    v.w = pk2(g2[ci+6]*W3[(ci+6)*CD+co], g2[ci+7]*W3[(ci+7)*CD+co]);
    W3F[e] = v;
  }
  if (tid < 32){
    int t4 = tid*4;
    uint2 v;
    v.x = pk2(g3[t4], g3[t4+1]);  v.y = pk2(g3[t4+2], g3[t4+3]);  Pg[tid] = v;
    v.x = pk2(be3[t4],be3[t4+1]); v.y = pk2(be3[t4+2],be3[t4+3]); Pb[tid] = v;
    v.x = pk2(W4[t4], W4[t4+1]);  v.y = pk2(W4[t4+2], W4[t4+3]);  Pw[tid] = v;
  }
  if (tid < 128) GC[tid] = gcomb[b*CD + tid];
  __syncthreads();

  const int wave = tid>>6, lane = tid&63;
  const int m = lane&15, g = lane>>4;
  const int wb = (blockIdx.x % 320)*4 + wave;  // 0..1279 within batch
  float dacc = 0.f;

#pragma unroll 1
  for (int rep = 0; rep < 2; ++rep){
    const int tb = wb + rep*1280;
    if (tb >= 2500) break;
    const size_t zb = ((size_t)(b*2500+tb)*4)*64 + lane;
    uint4 zf0 = z2g[zb];
    uint4 zf1 = z2g[zb+64];
    uint4 zf2 = z2g[zb+128];
    uint4 zf3 = z2g[zb+192];

    f4_t a3[8];
#pragma unroll
    for (int mt=0;mt<8;++mt) a3[mt]=(f4_t){0.f,0.f,0.f,0.f};
#pragma unroll
    for (int ks=0;ks<4;++ks){
      bf8_t Bf = bc8(ks==0?zf0:ks==1?zf1:ks==2?zf2:zf3);
#pragma unroll
      for (int mto=0;mto<8;++mto)
        a3[mto] = __builtin_amdgcn_mfma_f32_16x16x32_bf16(
                      bc8(W3F[(ks*8+mto)*64+lane]), Bf, a3[mto], 0,0,0);
    }

    float s1=0.f, s2=0.f;
#pragma unroll
    for (int mt=0;mt<8;++mt){
      float4 gcq = *reinterpret_cast<const float4*>(&GC[16*mt+4*g]);
      a3[mt][0]+=gcq.x; a3[mt][1]+=gcq.y; a3[mt][2]+=gcq.z; a3[mt][3]+=gcq.w;
#pragma unroll
      for (int r=0;r<4;++r){ float v=a3[mt][r]; s1+=v; s2=fmaf(v,v,s2); }
    }
    s1 += __shfl_xor(s1,16); s1 += __shfl_xor(s1,32);
    s2 += __shfl_xor(s2,16); s2 += __shfl_xor(s2,32);
    float mu = s1*(1.f/128.f);
    float rs = rsqrtf(fmaxf(s2*(1.f/128.f)-mu*mu,0.f)+1e-5f);

    float U = 0.f;
#pragma unroll
    for (int mt=0;mt<8;++mt){
      uint2 gv = Pg[4*mt+g], bv = Pb[4*mt+g], wv = Pw[4*mt+g];
      float h0 = fmaxf(0.f, fmaf((a3[mt][0]-mu)*rs, uplo(gv.x), uplo(bv.x)));
      float h1 = fmaxf(0.f, fmaf((a3[mt][1]-mu)*rs, uphi(gv.x), uphi(bv.x)));
      float h2 = fmaxf(0.f, fmaf((a3[mt][2]-mu)*rs, uplo(gv.y), uplo(bv.y)));
      float h3 = fmaxf(0.f, fmaf((a3[mt][3]-mu)*rs, uphi(gv.y), uphi(bv.y)));
      U = fmaf(h0, uplo(wv.x), U); U = fmaf(h1, uphi(wv.x), U);
      U = fmaf(h2, uplo(wv.y), U); U = fmaf(h3, uphi(wv.y), U);
    }
    U += __shfl_xor(U,16); U += __shfl_xor(U,32);
    float w = 2.f/(1.f + __expf(-U));
    const int n = tb*16 + m;
    float msk = masks[(size_t)(4*b+g)*NPTS + n];
    mwT[(size_t)(b*4+g)*NPTS + n] = f2bfu(msk*w);
    dacc += msk*w;
  }

  dacc += __shfl_xor(dacc,1); dacc += __shfl_xor(dacc,2);
  dacc += __shfl_xor(dacc,4); dacc += __shfl_xor(dacc,8);
  if (m==0) DEN[wave*4+g] = dacc;
  __syncthreads();
  if (tid < 4){
    float s = DEN[tid] + DEN[4+tid] + DEN[8+tid] + DEN[12+tid];
    atomicAdd(&denom[b*4+tid], s);
  }
}

// pooled[b,v,c] = sum_n mw[b,v,n]*feat[b,c,n]  — coalesced VALU reduction.
// grid 2016 = 4 b x 8 cgroup x 63 nchunk(640); block = 16 c-rows x 16 lanes.
__global__ __launch_bounds__(256)
void k_pool(const float* __restrict__ feat, const unsigned short* __restrict__ mwT,
            float* __restrict__ pool_acc)
{
  const int b   = blockIdx.x / 504;
  const int rem = blockIdx.x % 504;
  const int cg  = rem / 63;
  const int nch = rem % 63;
  const int cl  = threadIdx.x >> 4, ln = threadIdx.x & 15;
  const int c   = cg*16 + cl;
  const int n0  = nch*640;
  const float* f = &feat[((size_t)b*CD + c)*NPTS];
  const unsigned short* mw = &mwT[(size_t)b*4*NPTS];
  float a0=0.f, a1=0.f, a2=0.f, a3=0.f;
#pragma unroll
  for (int itr=0; itr<10; ++itr){
    int n = n0 + itr*64 + ln*4;
    if (n < NPTS){
      float4 fv = *reinterpret_cast<const float4*>(&f[n]);
      uint2 m0 = *reinterpret_cast<const uint2*>(&mw[0*NPTS+n]);
      uint2 m1 = *reinterpret_cast<const uint2*>(&mw[1*NPTS+n]);
      uint2 m2 = *reinterpret_cast<const uint2*>(&mw[2*NPTS+n]);
      uint2 m3 = *reinterpret_cast<const uint2*>(&mw[3*NPTS+n]);
      a0 = fmaf(fv.x,uplo(m0.x),a0); a0 = fmaf(fv.y,uphi(m0.x),a0);
      a0 = fmaf(fv.z,uplo(m0.y),a0); a0 = fmaf(fv.w,uphi(m0.y),a0);
      a1 = fmaf(fv.x,uplo(m1.x),a1); a1 = fmaf(fv.y,uphi(m1.x),a1);
      a1 = fmaf(fv.z,uplo(m1.y),a1); a1 = fmaf(fv.w,uphi(m1.y),a1);
      a2 = fmaf(fv.x,uplo(m2.x),a2); a2 = fmaf(fv.y,uphi(m2.x),a2);
      a2 = fmaf(fv.z,uplo(m2.y),a2); a2 = fmaf(fv.w,uphi(m2.y),a2);
      a3 = fmaf(fv.x,uplo(m3.x),a3); a3 = fmaf(fv.y,uphi(m3.x),a3);
      a3 = fmaf(fv.z,uplo(m3.y),a3); a3 = fmaf(fv.w,uphi(m3.y),a3);
    }
  }
#pragma unroll
  for (int o=1;o<16;o<<=1){
    a0 += __shfl_xor(a0,o); a1 += __shfl_xor(a1,o);
    a2 += __shfl_xor(a2,o); a3 += __shfl_xor(a3,o);
  }
  if (ln == 0){
    atomicAdd(&pool_acc[(b*4+0)*CD + c], a0);
    atomicAdd(&pool_acc[(b*4+1)*CD + c], a1);
    atomicAdd(&pool_acc[(b*4+2)*CD + c], a2);
    atomicAdd(&pool_acc[(b*4+3)*CD + c], a3);
  }
}

__global__ __launch_bounds__(256)
void k_final(const float* __restrict__ pool_acc, const float* __restrict__ denom,
             const float* __restrict__ globalv, float* __restrict__ out)
{
  int t = blockIdx.x*256 + threadIdx.x;   // 2048
  int bv = t>>7, c = t&127, b = bv>>2;
  out[t] = pool_acc[t]/(denom[bv]+1e-8f) + globalv[b*CD+c];
}

extern "C" void kernel_launch(void* const* d_in, const int* in_sizes, int n_in,
                              void* d_out, int out_size, void* d_ws,
                              size_t ws_size, hipStream_t stream) {
  const float* xyz  = (const float*)d_in[0];
  const float* feat = (const float*)d_in[1];
  const float* masks= (const float*)d_in[2];
  const float* W1 = (const float*)d_in[3];
  const float* b1 = (const float*)d_in[4];
  const float* g1 = (const float*)d_in[5];
  const float* be1= (const float*)d_in[6];
  const float* W2 = (const float*)d_in[7];
  const float* b2 = (const float*)d_in[8];
  const float* g2 = (const float*)d_in[9];
  const float* be2= (const float*)d_in[10];
  const float* W3 = (const float*)d_in[11];
  const float* b3 = (const float*)d_in[12];
  const float* g3 = (const float*)d_in[13];
  const float* be3= (const float*)d_in[14];
  const float* W4 = (const float*)d_in[15];
  float* out = (float*)d_out;

  char* ws = (char*)d_ws;
  float*    denom   = (float*)(ws + 4096);             // 64 B
  float*    pool_acc= (float*)(ws + 4352);             // 8 KB
  float*    globalv = (float*)(ws + 12544);            // 2 KB
  float*    gcomb   = (float*)(ws + 14592);            // 2 KB
  unsigned short* mwT = (unsigned short*)(ws + 16640); // 1.28 MB
  unsigned* pmax    = (unsigned*)(ws + 1310720);       // 256 KB
  unsigned* pmin    = (unsigned*)(ws + 1572864);       // 256 KB
  uint4*    z2g     = (uint4*)(ws + 5136640);          // 40.96 MB

  k_A<<<512, 256, 0, stream>>>(xyz, W1, b1, g1, be1, W2, b2, z2g,
                               denom, pool_acc);
  k_cpart<<<500, 256, 0, stream>>>(z2g, pmax, pmin);
  k_cred<<<4, 256, 0, stream>>>(pmax, pmin, g2, be2, W3, b3, globalv, gcomb);
  k_B<<<1280, 256, 0, stream>>>(z2g, g2, W3, g3, be3, W4, masks, gcomb,
                                mwT, denom);
  k_pool<<<2016, 256, 0, stream>>>(feat, mwT, pool_acc);
  k_final<<<8, 256, 0, stream>>>(pool_acc, denom, globalv, out);
}

// Round 15
// 105.978 us; speedup vs baseline: 1.9874x; 1.0408x over previous
//
#include <hip/hip_runtime.h>
#include <stdint.h>

// GeoAwarePooling B=4, N=40000, C=128, V=4.
// xyz is broadcast across views -> per-point MLP runs once over B*N points.
// v15: v13 structure unchanged; pk2 now emits v_cvt_pk_bf16_f32 via inline
// asm (no builtin exists on gfx950; __hip_bfloat162 isn't bit_cast-able) —
// 1 inst instead of ~12 VALU ops of manual RNE. k_A had 32 pk2 per tile on
// its critical path.

#define NPTS 40000
#define CD   128

typedef __attribute__((ext_vector_type(8))) short bf8_t;
typedef __attribute__((ext_vector_type(4))) float f4_t;

__device__ __forceinline__ unsigned short f2bfu(float f){
  unsigned u = __float_as_uint(f);
  u += 0x7FFFu + ((u>>16)&1u);               // RNE
  return (unsigned short)(u>>16);
}
__device__ __forceinline__ float bfhi_f(float f){   // f rounded to bf16, as f32
  return __uint_as_float(((unsigned)f2bfu(f))<<16);
}
__device__ __forceinline__ unsigned pk2(float a, float b){
  unsigned r;
  asm("v_cvt_pk_bf16_f32 %0, %1, %2" : "=v"(r) : "v"(a), "v"(b));
  return r;
}
__device__ __forceinline__ float uplo(unsigned u){ return __uint_as_float(u<<16); }
__device__ __forceinline__ float uphi(unsigned u){ return __uint_as_float(u & 0xFFFF0000u); }
__device__ __forceinline__ unsigned fenc(float f){  // order-preserving key
  unsigned u = __float_as_uint(f);
  return (u & 0x80000000u) ? ~u : (u | 0x80000000u);
}
__device__ __forceinline__ float fdec(unsigned k){
  return (k & 0x80000000u) ? __uint_as_float(k & 0x7FFFFFFFu) : __uint_as_float(~k);
}
__device__ __forceinline__ bf8_t bc8(uint4 v){ return __builtin_bit_cast(bf8_t, v); }

// ---------------------------------------------------------------------------
// Phase A: y=xyz@W1+b1 (K=32 MFMA, hi/lo split, fp32-exact); h=relu(LN1(y));
// z=(h@W2+b2 normalized, pre-affine) -> global in B-FRAGMENT layout:
// z2g[(it*4+ks)*64+lane]. 256 thr (4 waves), grid 512, 5 const-indexed reps.
// NO carried state across the body (spills otherwise: R6/R8/R11).
// Block 0 zero-inits denom/pool_acc (consumers are in later kernels).
// ---------------------------------------------------------------------------
__global__ __launch_bounds__(256)
void k_A(const float* __restrict__ xyz,
         const float* __restrict__ W1, const float* __restrict__ b1,
         const float* __restrict__ g1, const float* __restrict__ be1,
         const float* __restrict__ W2, const float* __restrict__ b2,
         uint4* __restrict__ z2g,
         float* __restrict__ denom, float* __restrict__ pool_acc)
{
  __shared__ uint4 W2F[2048];        // 32 KiB  [frag=ks*8+mto][lane]
  __shared__ uint4 A1F[512];         // 8 KiB   [mto][lane]
  __shared__ uint4 Hb4[4][16][16];   // 16 KiB  per-wave transpose tile
  __shared__ uint2 P1u[32], P2u[32], P3u[32];

  const int tid = threadIdx.x;
  if (blockIdx.x == 0){
    if (tid < 16) denom[tid] = 0.f;
    for (int i = tid; i < 2048; i += 256) pool_acc[i] = 0.f;
  }
  for (int e = tid; e < 2048; e += 256){
    int f = e >> 6, l = e & 63;
    int ks = f >> 3, mto = f & 7;
    int lm = l & 15, lg = l >> 4;
    int ci = 32*ks + 8*lg, co = 16*mto + lm;
    uint4 v;
    v.x = pk2(W2[(ci+0)*CD+co], W2[(ci+1)*CD+co]);
    v.y = pk2(W2[(ci+2)*CD+co], W2[(ci+3)*CD+co]);
    v.z = pk2(W2[(ci+4)*CD+co], W2[(ci+5)*CD+co]);
    v.w = pk2(W2[(ci+6)*CD+co], W2[(ci+7)*CD+co]);
    W2F[e] = v;
  }
  for (int e = tid; e < 512; e += 256){
    int mto = e >> 6, l = e & 63;
    int lm = l & 15, lg = l >> 4;
    int c = 16*mto + lm;
    float w0=W1[c], w1=W1[CD+c], w2=W1[2*CD+c], bb=b1[c];
    uint4 v = {0u,0u,0u,0u};
    if (lg==0){ v.x=pk2(w0,w1); v.y=pk2(w2,w0); v.z=pk2(w1,w2);
                v.w=pk2(w0-bfhi_f(w0), w1-bfhi_f(w1)); }
    else if (lg==1){ v.x=pk2(w2-bfhi_f(w2), bb); v.y=pk2(bb-bfhi_f(bb),0.f); }
    A1F[e] = v;
  }
  if (tid < 32){
    int t4 = tid*4;
    uint2 v;
    v.x = pk2(g1[t4], g1[t4+1]);  v.y = pk2(g1[t4+2], g1[t4+3]);  P1u[tid] = v;
    v.x = pk2(be1[t4],be1[t4+1]); v.y = pk2(be1[t4+2],be1[t4+3]); P2u[tid] = v;
    v.x = pk2(b2[t4], b2[t4+1]);  v.y = pk2(b2[t4+2], b2[t4+3]);  P3u[tid] = v;
  }
  __syncthreads();

  const int wave = tid>>6, lane = tid&63;
  const int m = lane&15, g = lane>>4;
  const int b  = blockIdx.x >> 7;              // 128 blocks per batch
  const int wb = (blockIdx.x & 127)*4 + wave;  // 0..511 within batch
  const int swz = m & 7;
  const float* xyzb = xyz + (size_t)3*b*NPTS;
  uint2* Hb2 = (uint2*)&Hb4[wave][0][0];

#pragma unroll 1
  for (int rep = 0; rep < 5; ++rep){
    const int tb = wb + rep*512;
    if (tb >= 2500) break;
    const int it = b*2500 + tb;
    const int n = tb*16 + m;
    float px = xyzb[n], py = xyzb[NPTS+n], pz = xyzb[2*NPTS+n];

    uint4 B1u = {0u,0u,0u,0u};
    if (g==0){ B1u.x = pk2(px,py); B1u.y = pk2(pz, px-bfhi_f(px));
               B1u.z = pk2(py-bfhi_f(py), pz-bfhi_f(pz)); B1u.w = pk2(px,py); }
    else if (g==1){ B1u.x = pk2(pz, 1.0f); B1u.y = pk2(1.0f, 0.f); }
    bf8_t B1 = bc8(B1u);

    // GEMM1
    f4_t acc[8];
#pragma unroll
    for (int mt=0;mt<8;++mt)
      acc[mt] = __builtin_amdgcn_mfma_f32_16x16x32_bf16(
                    bc8(A1F[mt*64+lane]), B1, (f4_t){0.f,0.f,0.f,0.f}, 0,0,0);

    // LN1
    float s1=0.f, s2=0.f;
#pragma unroll
    for (int mt=0;mt<8;++mt)
#pragma unroll
      for (int r=0;r<4;++r){ float v=acc[mt][r]; s1+=v; s2=fmaf(v,v,s2); }
    s1 += __shfl_xor(s1,16); s1 += __shfl_xor(s1,32);
    s2 += __shfl_xor(s2,16); s2 += __shfl_xor(s2,32);
    float mu = s1*(1.f/128.f);
    float rs = rsqrtf(fmaxf(s2*(1.f/128.f)-mu*mu,0.f)+1e-5f);

    // affine+relu -> write h pairs into swizzled transpose tile
#pragma unroll
    for (int mt=0;mt<8;++mt){
      uint2 gv = P1u[4*mt+g], bv = P2u[4*mt+g];
      float h0 = fmaxf(0.f, fmaf((acc[mt][0]-mu)*rs, uplo(gv.x), uplo(bv.x)));
      float h1 = fmaxf(0.f, fmaf((acc[mt][1]-mu)*rs, uphi(gv.x), uphi(bv.x)));
      float h2 = fmaxf(0.f, fmaf((acc[mt][2]-mu)*rs, uplo(gv.y), uplo(bv.y)));
      float h3 = fmaxf(0.f, fmaf((acc[mt][3]-mu)*rs, uphi(gv.y), uphi(bv.y)));
      uint2 wv; wv.x = pk2(h0,h1); wv.y = pk2(h2,h3);
      int slot = ((mt>>1)*4 + 2*(mt&1) + (g>>1)) ^ swz;
      Hb2[(m*16 + slot)*2 + (g&1)] = wv;
    }

    // GEMM2: B-frags from transpose tile, A-frags from W2F
    f4_t a2[8];
#pragma unroll
    for (int mt=0;mt<8;++mt) a2[mt]=(f4_t){0.f,0.f,0.f,0.f};
#pragma unroll
    for (int ks=0;ks<4;++ks){
      bf8_t Bf = bc8(Hb4[wave][m][(ks*4+g)^swz]);
#pragma unroll
      for (int mto=0;mto<8;++mto)
        a2[mto] = __builtin_amdgcn_mfma_f32_16x16x32_bf16(
                      bc8(W2F[(ks*8+mto)*64+lane]), Bf, a2[mto], 0,0,0);
    }

    // +b2, LN2
    s1=0.f; s2=0.f;
#pragma unroll
    for (int mt=0;mt<8;++mt){
      uint2 bv = P3u[4*mt+g];
      a2[mt][0]+=uplo(bv.x); a2[mt][1]+=uphi(bv.x);
      a2[mt][2]+=uplo(bv.y); a2[mt][3]+=uphi(bv.y);
#pragma unroll
      for (int r=0;r<4;++r){ float v=a2[mt][r]; s1+=v; s2=fmaf(v,v,s2); }
    }
    s1 += __shfl_xor(s1,16); s1 += __shfl_xor(s1,32);
    s2 += __shfl_xor(s2,16); s2 += __shfl_xor(s2,32);
    mu = s1*(1.f/128.f);
    rs = rsqrtf(fmaxf(s2*(1.f/128.f)-mu*mu,0.f)+1e-5f);

    // z pairs -> transpose tile -> read frags -> coalesced global store
#pragma unroll
    for (int mt=0;mt<8;++mt){
      float z0=(a2[mt][0]-mu)*rs, z1=(a2[mt][1]-mu)*rs;
      float z2v=(a2[mt][2]-mu)*rs, z3=(a2[mt][3]-mu)*rs;
      uint2 wv; wv.x=pk2(z0,z1); wv.y=pk2(z2v,z3);
      int slot = ((mt>>1)*4 + 2*(mt&1) + (g>>1)) ^ swz;
      Hb2[(m*16 + slot)*2 + (g&1)] = wv;
    }
#pragma unroll
    for (int ks=0;ks<4;++ks){
      uint4 frag = Hb4[wave][m][(ks*4+g)^swz];
      z2g[(size_t)(it*4+ks)*64 + lane] = frag;
    }
  }
}

__device__ __forceinline__ void upd8(uint4 v, float mx[8], float mn[8]){
  mx[0]=fmaxf(mx[0],uplo(v.x)); mn[0]=fminf(mn[0],uplo(v.x));
  mx[1]=fmaxf(mx[1],uphi(v.x)); mn[1]=fminf(mn[1],uphi(v.x));
  mx[2]=fmaxf(mx[2],uplo(v.y)); mn[2]=fminf(mn[2],uplo(v.y));
  mx[3]=fmaxf(mx[3],uphi(v.y)); mn[3]=fminf(mn[3],uphi(v.y));
  mx[4]=fmaxf(mx[4],uplo(v.z)); mn[4]=fminf(mn[4],uplo(v.z));
  mx[5]=fmaxf(mx[5],uphi(v.z)); mn[5]=fminf(mn[5],uphi(v.z));
  mx[6]=fmaxf(mx[6],uplo(v.w)); mn[6]=fminf(mn[6],uplo(v.w));
  mx[7]=fmaxf(mx[7],uphi(v.w)); mn[7]=fminf(mn[7],uphi(v.w));
}

// Stage 1: per-block partial max/min of z2 (frag layout), ZERO atomics.
// 500 blocks = 4 batches x 125; each block scans 20 tiles (4-unrolled loads)
// and stores fenc-encoded partials: pmax[b][125][128], pmin[b][125][128].
__global__ __launch_bounds__(256)
void k_cpart(const uint4* __restrict__ z2g,
             unsigned* __restrict__ pmax, unsigned* __restrict__ pmin)
{
  const int wave = threadIdx.x>>6, lane = threadIdx.x&63;
  const int m = lane&15, g = lane>>4;
  const int blk = blockIdx.x;
  const int b = blk/125, ib = blk%125;
  const int ks = wave;
  float mx[8], mn[8];
#pragma unroll
  for (int j=0;j<8;++j){ mx[j]=-1e30f; mn[j]=1e30f; }
  const uint4* base = z2g + (((size_t)(b*2500 + ib*20))*4 + ks)*64 + lane;
#pragma unroll 1
  for (int t=0;t<20;t+=4){
    uint4 v0 = base[(size_t)(t+0)*256];
    uint4 v1 = base[(size_t)(t+1)*256];
    uint4 v2 = base[(size_t)(t+2)*256];
    uint4 v3 = base[(size_t)(t+3)*256];
    upd8(v0, mx, mn); upd8(v1, mx, mn); upd8(v2, mx, mn); upd8(v3, mx, mn);
  }
#pragma unroll
  for (int j=0;j<8;++j){
#pragma unroll
    for (int o=1;o<16;o<<=1){
      mx[j]=fmaxf(mx[j],__shfl_xor(mx[j],o));
      mn[j]=fminf(mn[j],__shfl_xor(mn[j],o));
    }
  }
  if (m==0){
    size_t row = ((size_t)b*125 + ib)*128 + 32*ks + 8*g;
#pragma unroll
    for (int j=0;j<8;++j){
      pmax[row+j] = fenc(mx[j]);
      pmin[row+j] = fenc(mn[j]);
    }
  }
}

// Stage 2: reduce 125 partials/channel -> global_xyz; then
// gcomb = b3 + be2@W3top + global@W3bot. 4 blocks (one per batch).
__global__ __launch_bounds__(256)
void k_cred(const unsigned* __restrict__ pmax, const unsigned* __restrict__ pmin,
            const float* __restrict__ g2, const float* __restrict__ be2,
            const float* __restrict__ W3, const float* __restrict__ b3,
            float* __restrict__ globalv, float* __restrict__ gcomb)
{
  __shared__ float ZX[128], ZN[128], GS[128], BS[128], PART[256];
  const int b = blockIdx.x, tid = threadIdx.x;
  {
    const int c = tid & 127;
    if (tid < 128){
      unsigned k = 0u;
      const unsigned* p = pmax + (size_t)b*125*128 + c;
#pragma unroll 5
      for (int i=0;i<125;++i) k = max(k, p[(size_t)i*128]);
      ZX[c] = fdec(k);
    } else {
      unsigned k = 0xFFFFFFFFu;
      const unsigned* p = pmin + (size_t)b*125*128 + c;
#pragma unroll 5
      for (int i=0;i<125;++i) k = min(k, p[(size_t)i*128]);
      ZN[c] = fdec(k);
    }
  }
  __syncthreads();
  if (tid < 128){
    float gg = g2[tid];
    float gl = (gg>=0.f ? gg*ZX[tid] : gg*ZN[tid]) + be2[tid];
    GS[tid] = gl;
    globalv[b*CD+tid] = gl;
    BS[tid] = be2[tid];
  }
  __syncthreads();
  {
    int c = tid & 127, half = tid >> 7;
    float accv = 0.f;
    if (half==0){
      for (int k=0;k<128;++k) accv = fmaf(BS[k], W3[k*CD+c], accv);
      accv += b3[c];
    } else {
      for (int k=0;k<128;++k) accv = fmaf(GS[k], W3[(128+k)*CD+c], accv);
    }
    PART[tid] = accv;
  }
  __syncthreads();
  if (tid < 128) gcomb[b*CD+tid] = PART[tid] + PART[128+tid];
}

// ---------------------------------------------------------------------------
// Phase B: u = z2@(g2*W3top) + gcomb; h2=relu(LN3(u)); w=2*sigmoid(h2@W4).
// Low-VGPR body (direct just-in-time z loads, precomputed gcomb) at
// 256 thr, grid 1280 (4 blocks/CU by LDS -> 16 waves/CU), 2 strided reps.
// Block-LDS denom pre-reduce (1 atomic set per block).
// ---------------------------------------------------------------------------
__global__ __launch_bounds__(256)
void k_B(const uint4* __restrict__ z2g, const float* __restrict__ g2,
         const float* __restrict__ W3, const float* __restrict__ g3,
         const float* __restrict__ be3, const float* __restrict__ W4,
         const float* __restrict__ masks, const float* __restrict__ gcomb,
         unsigned short* __restrict__ mwT, float* __restrict__ denom)
{
  __shared__ uint4 W3F[2048];        // 32 KiB, g2 folded into rows
  __shared__ uint2 Pg[32], Pb[32], Pw[32];
  __shared__ float GC[128];
  __shared__ float DEN[16];

  const int tid = threadIdx.x;
  const int b = blockIdx.x / 320;              // 320 blocks per batch
  for (int e = tid; e < 2048; e += 256){
    int f = e >> 6, l = e & 63;
    int ks = f >> 3, mto = f & 7;
    int lm = l & 15, lg = l >> 4;
    int ci = 32*ks + 8*lg, co = 16*mto + lm;
    uint4 v;
    v.x = pk2(g2[ci+0]*W3[(ci+0)*CD+co], g2[ci+1]*W3[(ci+1)*CD+co]);
    v.y = pk2(g2[ci+2]*W3[(ci+2)*CD+co], g2[ci+3]*W3[(ci+3)*CD+co]);
    v.z = pk2(g2[ci+4]*W3[(ci+4)*CD+co], g2[ci+5]*W3[(ci+5)*CD+co]);
    v.w = pk2(g2[ci+6]*W3[(ci+6)*CD+co], g2[ci+7]*W3[(ci+7)*CD+co]);
    W3F[e] = v;
  }
  if (tid < 32){
    int t4 = tid*4;
    uint2 v;
    v.x = pk2(g3[t4], g3[t4+1]);  v.y = pk2(g3[t4+2], g3[t4+3]);  Pg[tid] = v;
    v.x = pk2(be3[t4],be3[t4+1]); v.y = pk2(be3[t4+2],be3[t4+3]); Pb[tid] = v;
    v.x = pk2(W4[t4], W4[t4+1]);  v.y = pk2(W4[t4+2], W4[t4+3]);  Pw[tid] = v;
  }
  if (tid < 128) GC[tid] = gcomb[b*CD + tid];
  __syncthreads();

  const int wave = tid>>6, lane = tid&63;
  const int m = lane&15, g = lane>>4;
  const int wb = (blockIdx.x % 320)*4 + wave;  // 0..1279 within batch
  float dacc = 0.f;

#pragma unroll 1
  for (int rep = 0; rep < 2; ++rep){
    const int tb = wb + rep*1280;
    if (tb >= 2500) break;
    const size_t zb = ((size_t)(b*2500+tb)*4)*64 + lane;
    uint4 zf0 = z2g[zb];
    uint4 zf1 = z2g[zb+64];
    uint4 zf2 = z2g[zb+128];
    uint4 zf3 = z2g[zb+192];

    f4_t a3[8];
#pragma unroll
    for (int mt=0;mt<8;++mt) a3[mt]=(f4_t){0.f,0.f,0.f,0.f};
#pragma unroll
    for (int ks=0;ks<4;++ks){
      bf8_t Bf = bc8(ks==0?zf0:ks==1?zf1:ks==2?zf2:zf3);
#pragma unroll
      for (int mto=0;mto<8;++mto)
        a3[mto] = __builtin_amdgcn_mfma_f32_16x16x32_bf16(
                      bc8(W3F[(ks*8+mto)*64+lane]), Bf, a3[mto], 0,0,0);
    }

    float s1=0.f, s2=0.f;
#pragma unroll
    for (int mt=0;mt<8;++mt){
      float4 gcq = *reinterpret_cast<const float4*>(&GC[16*mt+4*g]);
      a3[mt][0]+=gcq.x; a3[mt][1]+=gcq.y; a3[mt][2]+=gcq.z; a3[mt][3]+=gcq.w;
#pragma unroll
      for (int r=0;r<4;++r){ float v=a3[mt][r]; s1+=v; s2=fmaf(v,v,s2); }
    }
    s1 += __shfl_xor(s1,16); s1 += __shfl_xor(s1,32);
    s2 += __shfl_xor(s2,16); s2 += __shfl_xor(s2,32);
    float mu = s1*(1.f/128.f);
    float rs = rsqrtf(fmaxf(s2*(1.f/128.f)-mu*mu,0.f)+1e-5f);

    float U = 0.f;
#pragma unroll
    for (int mt=0;mt<8;++mt){
      uint2 gv = Pg[4*mt+g], bv = Pb[4*mt+g], wv = Pw[4*mt+g];
      float h0 = fmaxf(0.f, fmaf((a3[mt][0]-mu)*rs, uplo(gv.x), uplo(bv.x)));
      float h1 = fmaxf(0.f, fmaf((a3[mt][1]-mu)*rs, uphi(gv.x), uphi(bv.x)));
      float h2 = fmaxf(0.f, fmaf((a3[mt][2]-mu)*rs, uplo(gv.y), uplo(bv.y)));
      float h3 = fmaxf(0.f, fmaf((a3[mt][3]-mu)*rs, uphi(gv.y), uphi(bv.y)));
      U = fmaf(h0, uplo(wv.x), U); U = fmaf(h1, uphi(wv.x), U);
      U = fmaf(h2, uplo(wv.y), U); U = fmaf(h3, uphi(wv.y), U);
    }
    U += __shfl_xor(U,16); U += __shfl_xor(U,32);
    float w = 2.f/(1.f + __expf(-U));
    const int n = tb*16 + m;
    float msk = masks[(size_t)(4*b+g)*NPTS + n];
    mwT[(size_t)(b*4+g)*NPTS + n] = f2bfu(msk*w);
    dacc += msk*w;
  }

  dacc += __shfl_xor(dacc,1); dacc += __shfl_xor(dacc,2);
  dacc += __shfl_xor(dacc,4); dacc += __shfl_xor(dacc,8);
  if (m==0) DEN[wave*4+g] = dacc;
  __syncthreads();
  if (tid < 4){
    float s = DEN[tid] + DEN[4+tid] + DEN[8+tid] + DEN[12+tid];
    atomicAdd(&denom[b*4+tid], s);
  }
}

// pooled[b,v,c] = sum_n mw[b,v,n]*feat[b,c,n]  — coalesced VALU reduction.
// grid 2016 = 4 b x 8 cgroup x 63 nchunk(640); block = 16 c-rows x 16 lanes.
__global__ __launch_bounds__(256)
void k_pool(const float* __restrict__ feat, const unsigned short* __restrict__ mwT,
            float* __restrict__ pool_acc)
{
  const int b   = blockIdx.x / 504;
  const int rem = blockIdx.x % 504;
  const int cg  = rem / 63;
  const int nch = rem % 63;
  const int cl  = threadIdx.x >> 4, ln = threadIdx.x & 15;
  const int c   = cg*16 + cl;
  const int n0  = nch*640;
  const float* f = &feat[((size_t)b*CD + c)*NPTS];
  const unsigned short* mw = &mwT[(size_t)b*4*NPTS];
  float a0=0.f, a1=0.f, a2=0.f, a3=0.f;
#pragma unroll
  for (int itr=0; itr<10; ++itr){
    int n = n0 + itr*64 + ln*4;
    if (n < NPTS){
      float4 fv = *reinterpret_cast<const float4*>(&f[n]);
      uint2 m0 = *reinterpret_cast<const uint2*>(&mw[0*NPTS+n]);
      uint2 m1 = *reinterpret_cast<const uint2*>(&mw[1*NPTS+n]);
      uint2 m2 = *reinterpret_cast<const uint2*>(&mw[2*NPTS+n]);
      uint2 m3 = *reinterpret_cast<const uint2*>(&mw[3*NPTS+n]);
      a0 = fmaf(fv.x,uplo(m0.x),a0); a0 = fmaf(fv.y,uphi(m0.x),a0);
      a0 = fmaf(fv.z,uplo(m0.y),a0); a0 = fmaf(fv.w,uphi(m0.y),a0);
      a1 = fmaf(fv.x,uplo(m1.x),a1); a1 = fmaf(fv.y,uphi(m1.x),a1);
      a1 = fmaf(fv.z,uplo(m1.y),a1); a1 = fmaf(fv.w,uphi(m1.y),a1);
      a2 = fmaf(fv.x,uplo(m2.x),a2); a2 = fmaf(fv.y,uphi(m2.x),a2);
      a2 = fmaf(fv.z,uplo(m2.y),a2); a2 = fmaf(fv.w,uphi(m2.y),a2);
      a3 = fmaf(fv.x,uplo(m3.x),a3); a3 = fmaf(fv.y,uphi(m3.x),a3);
      a3 = fmaf(fv.z,uplo(m3.y),a3); a3 = fmaf(fv.w,uphi(m3.y),a3);
    }
  }
#pragma unroll
  for (int o=1;o<16;o<<=1){
    a0 += __shfl_xor(a0,o); a1 += __shfl_xor(a1,o);
    a2 += __shfl_xor(a2,o); a3 += __shfl_xor(a3,o);
  }
  if (ln == 0){
    atomicAdd(&pool_acc[(b*4+0)*CD + c], a0);
    atomicAdd(&pool_acc[(b*4+1)*CD + c], a1);
    atomicAdd(&pool_acc[(b*4+2)*CD + c], a2);
    atomicAdd(&pool_acc[(b*4+3)*CD + c], a3);
  }
}

__global__ __launch_bounds__(256)
void k_final(const float* __restrict__ pool_acc, const float* __restrict__ denom,
             const float* __restrict__ globalv, float* __restrict__ out)
{
  int t = blockIdx.x*256 + threadIdx.x;   // 2048
  int bv = t>>7, c = t&127, b = bv>>2;
  out[t] = pool_acc[t]/(denom[bv]+1e-8f) + globalv[b*CD+c];
}

extern "C" void kernel_launch(void* const* d_in, const int* in_sizes, int n_in,
                              void* d_out, int out_size, void* d_ws,
                              size_t ws_size, hipStream_t stream) {
  const float* xyz  = (const float*)d_in[0];
  const float* feat = (const float*)d_in[1];
  const float* masks= (const float*)d_in[2];
  const float* W1 = (const float*)d_in[3];
  const float* b1 = (const float*)d_in[4];
  const float* g1 = (const float*)d_in[5];
  const float* be1= (const float*)d_in[6];
  const float* W2 = (const float*)d_in[7];
  const float* b2 = (const float*)d_in[8];
  const float* g2 = (const float*)d_in[9];
  const float* be2= (const float*)d_in[10];
  const float* W3 = (const float*)d_in[11];
  const float* b3 = (const float*)d_in[12];
  const float* g3 = (const float*)d_in[13];
  const float* be3= (const float*)d_in[14];
  const float* W4 = (const float*)d_in[15];
  float* out = (float*)d_out;

  char* ws = (char*)d_ws;
  float*    denom   = (float*)(ws + 4096);             // 64 B
  float*    pool_acc= (float*)(ws + 4352);             // 8 KB
  float*    globalv = (float*)(ws + 12544);            // 2 KB
  float*    gcomb   = (float*)(ws + 14592);            // 2 KB
  unsigned short* mwT = (unsigned short*)(ws + 16640); // 1.28 MB
  unsigned* pmax    = (unsigned*)(ws + 1310720);       // 256 KB
  unsigned* pmin    = (unsigned*)(ws + 1572864);       // 256 KB
  uint4*    z2g     = (uint4*)(ws + 5136640);          // 40.96 MB

  k_A<<<512, 256, 0, stream>>>(xyz, W1, b1, g1, be1, W2, b2, z2g,
                               denom, pool_acc);
  k_cpart<<<500, 256, 0, stream>>>(z2g, pmax, pmin);
  k_cred<<<4, 256, 0, stream>>>(pmax, pmin, g2, be2, W3, b3, globalv, gcomb);
  k_B<<<1280, 256, 0, stream>>>(z2g, g2, W3, g3, be3, W4, masks, gcomb,
                                mwT, denom);
  k_pool<<<2016, 256, 0, stream>>>(feat, mwT, pool_acc);
  k_final<<<8, 256, 0, stream>>>(pool_acc, denom, globalv, out);
}